// Round 10
// baseline (422.532 us; speedup 1.0000x reference)
//
#include <hip/hip_runtime.h>
#include <hip/hip_bf16.h>

#define TPB 256
static constexpr int BATCH = 4;
static constexpr int NPTS  = 4096;
static constexpr int BN    = BATCH * NPTS;   // 16384 columns for all GEMMs

typedef __attribute__((ext_vector_type(8))) short short8v;
typedef __attribute__((ext_vector_type(4))) short short4v;
typedef __attribute__((ext_vector_type(4))) float f32x4;

struct Seg { const float* in; const float* W; int C; int ws; };

__device__ __forceinline__ void gload16(const void* g, void* l) {
    __builtin_amdgcn_global_load_lds(
        (const __attribute__((address_space(1))) void*)g,
        (__attribute__((address_space(3))) void*)l, 16, 0, 0);
}

// ---------------------------------------------------------------------------
// MFMA GEMM: D[m][col] = bias[m] + sum_k A[m][k]*B[k][col]
//   A: bf16 [M][Kp] row-major (Kp % 64 == 0), B: bf16 [Kp][BN] row-major.
// Block 256 thr = 4 waves; tile 128x128, BK=64; wave quadrant 64x64 (4x4 frags).
// A-tile: global_load_lds, source-address XOR swizzle, LDS [row][64k] 128B rows.
// B-tile: reg-staged (2x global dwordx4: 8 cols x k-pair) -> ds_write_b32 into
//   k-contiguous LDS [col][64k] with 136B row stride (conflict-free reads).
// Both fragments use slot->k map mu(g4,e)=g4*4+(e&3)+16*(e>>2) (same map on A
// and B => result independent of the HW k-permutation; mu bijective on [0,32)).
// No inline asm: __syncthreads() drains vmcnt (global_load_lds) + lgkmcnt.
// EPI 0: f32 out (+bias). EPI 1: bf16 out (+bias+relu) at row offset rowOff.
// ---------------------------------------------------------------------------
template<int EPI>
__global__ __launch_bounds__(256)
void gemm_k(const __hip_bfloat16* __restrict__ A, const __hip_bfloat16* __restrict__ B,
            const float* __restrict__ bias, float* __restrict__ outF,
            __hip_bfloat16* __restrict__ outB, int Kp, int rowOff)
{
    __shared__ short Alds[8192];   // 128 rows x 64 k (16 KB), 128B rows
    __shared__ short Blds[8704];   // 128 cols x 68 shorts (136B rows, 17 KB)
    const int tid = threadIdx.x, lane = tid & 63, wid = tid >> 6;
    const int wm = wid & 1, wn = wid >> 1;
    const int n0 = blockIdx.x * 128, m0 = blockIdx.y * 128;

    // ---- A staging setup: 1024 granules of 16B, 4 per thread (gload16) ----
    const char* asrc[4]; short* adst[4];
    #pragma unroll
    for (int t = 0; t < 4; ++t) {
        const int g = (wid * 4 + t) * 64 + lane;
        const int arow = g >> 3, ai = g & 7;
        asrc[t] = (const char*)A +
                  (((size_t)(m0 + arow)) * Kp + ((ai ^ (arow & 7)) << 3)) * 2;
        adst[t] = &Alds[(wid * 4 + t) * 512];   // wave-uniform base; HW adds lane*16
    }
    // ---- B staging setup: item q = it*256+tid -> kp = q>>4 (k-pair), c8 = q&15
    const char* bsrc[2]; int bkp[2], bc0[2];
    #pragma unroll
    for (int it = 0; it < 2; ++it) {
        const int q = it * 256 + tid;
        bkp[it] = q >> 4;          // k-pair index 0..31 (k = 2*kp, 2*kp+1)
        bc0[it] = (q & 15) * 8;    // first of 8 columns
        bsrc[it] = (const char*)B +
                   (((size_t)(bkp[it] * 2)) * BN + (n0 + bc0[it])) * 2;
    }

    f32x4 acc[4][4];
    #pragma unroll
    for (int i = 0; i < 4; ++i)
        #pragma unroll
        for (int j = 0; j < 4; ++j) acc[i][j] = (f32x4){0.f, 0.f, 0.f, 0.f};

    const int rl = lane & 15, g4 = lane >> 4;

    const int nkt = Kp >> 6;
    for (int kt = 0; kt < nkt; ++kt) {
        __syncthreads();   // previous iteration's LDS reads complete

        // B: load 8 cols x (k, k+1) into regs (coalesced 16B loads)
        short8v blo[2], bhi[2];
        #pragma unroll
        for (int it = 0; it < 2; ++it) {
            blo[it] = *(const short8v*)(bsrc[it]);
            bhi[it] = *(const short8v*)(bsrc[it] + (size_t)BN * 2);
            bsrc[it] += (size_t)64 * BN * 2;   // advance 64 k-rows
        }
        // A: async global->LDS
        #pragma unroll
        for (int t = 0; t < 4; ++t) {
            gload16(asrc[t], adst[t]);
            asrc[t] += 128;                    // +64 k
        }
        // B: transpose into LDS [col][k] via ds_write_b32 (k-pairs)
        #pragma unroll
        for (int it = 0; it < 2; ++it) {
            #pragma unroll
            for (int j = 0; j < 8; ++j) {
                const int c = bc0[it] + j;
                const int val = ((int)(unsigned short)blo[it][j]) |
                                (((int)(unsigned short)bhi[it][j]) << 16);
                *(int*)((char*)Blds + c * 136 + bkp[it] * 4) = val;
            }
        }
        __syncthreads();   // drains vmcnt(gload_lds) + lgkmcnt(ds_write) + barrier

        #pragma unroll
        for (int ks = 0; ks < 2; ++ks) {
            // A fragments (XOR-swizzled rows)
            short8v af[4];
            #pragma unroll
            for (int mf = 0; mf < 4; ++mf) {
                const int row = wm * 64 + mf * 16 + rl;
                const int base = row * 128, sw = (row & 7) << 4;
                const short4v lo = *(const short4v*)((const char*)Alds +
                                    (base + ((ks * 64 + (g4 << 3)) ^ sw)));
                const short4v hi = *(const short4v*)((const char*)Alds +
                                    (base + ((ks * 64 + (g4 << 3) + 32) ^ sw)));
                af[mf] = __builtin_shufflevector(lo, hi, 0,1,2,3,4,5,6,7);
            }
            // B fragments (linear 136B-stride rows; conflict-free)
            short8v bfv[4];
            #pragma unroll
            for (int nf = 0; nf < 4; ++nf) {
                const int colr = wn * 64 + nf * 16 + rl;
                const char* bp = (const char*)Blds + colr * 136 + ks * 64 + (g4 << 3);
                const short4v lo = *(const short4v*)bp;
                const short4v hi = *(const short4v*)(bp + 32);
                bfv[nf] = __builtin_shufflevector(lo, hi, 0,1,2,3,4,5,6,7);
            }
            #pragma unroll
            for (int mf = 0; mf < 4; ++mf)
                #pragma unroll
                for (int nf = 0; nf < 4; ++nf)
                    acc[mf][nf] = __builtin_amdgcn_mfma_f32_16x16x32_bf16(
                        af[mf], bfv[nf], acc[mf][nf], 0, 0, 0);
        }
    }

    #pragma unroll
    for (int mf = 0; mf < 4; ++mf) {
        #pragma unroll
        for (int i = 0; i < 4; ++i) {
            const int row = m0 + wm * 64 + mf * 16 + g4 * 4 + i;
            const float bs = bias[row];
            #pragma unroll
            for (int nf = 0; nf < 4; ++nf) {
                const int col = n0 + wn * 64 + nf * 16 + rl;
                float v = acc[mf][nf][i] + bs;
                if (EPI == 1) {
                    v = fmaxf(v, 0.f);
                    outB[(size_t)(rowOff + row) * BN + col] = __float2bfloat16(v);
                } else {
                    outF[(size_t)row * BN + col] = v;
                }
            }
        }
    }
}

// ---------------------------------------------------------------------------
// small f32 conv (kept for h1/h2 only)
// ---------------------------------------------------------------------------
template<bool RELU>
__global__ __launch_bounds__(TPB)
void conv1x1_k(Seg s0, Seg s1, int nseg, int Ctot,
               const float* __restrict__ bias, float* __restrict__ out, int O)
{
    __shared__ float Wl[131][16];
    const int n  = blockIdx.x * TPB + threadIdx.x;
    const int o0 = blockIdx.y * 16;
    const int b  = blockIdx.z;
    Seg segs[2] = {s0, s1};
    int off[3]; off[0] = 0;
    #pragma unroll
    for (int k = 0; k < 2; ++k) off[k + 1] = off[k] + (k < nseg ? segs[k].C : 0);
    for (int idx = threadIdx.x; idx < Ctot * 16; idx += TPB) {
        int c = idx >> 4, t = idx & 15;
        int k = (nseg > 1 && c >= off[1]) ? 1 : 0;
        Wl[c][t] = segs[k].W[(size_t)(o0 + t) * segs[k].ws + (c - off[k])];
    }
    __syncthreads();
    float acc[16];
    #pragma unroll
    for (int t = 0; t < 16; ++t) acc[t] = 0.f;
    int cbase = 0;
    for (int k = 0; k < nseg; ++k) {
        const float* ip = segs[k].in + (size_t)b * segs[k].C * NPTS + n;
        const int C = segs[k].C;
        #pragma unroll 4
        for (int cc = 0; cc < C; ++cc) {
            float v = ip[(size_t)cc * NPTS];
            const float4* wr = (const float4*)(&Wl[cbase + cc][0]);
            #pragma unroll
            for (int q = 0; q < 4; ++q) {
                float4 w = wr[q];
                acc[4*q+0] += w.x * v; acc[4*q+1] += w.y * v;
                acc[4*q+2] += w.z * v; acc[4*q+3] += w.w * v;
            }
        }
        cbase += C;
    }
    #pragma unroll
    for (int t = 0; t < 16; ++t) {
        float r = acc[t] + bias[o0 + t];
        if (RELU) r = fmaxf(r, 0.f);
        out[((size_t)b * O + o0 + t) * NPTS + n] = r;
    }
}

// ---------------------------------------------------------------------------
__global__ __launch_bounds__(TPB)
void wcomp_k(const float* __restrict__ Wr1, const float* __restrict__ Wn1,
             const float* __restrict__ Wl2, const float* __restrict__ bl2,
             const float* __restrict__ b1,
             float* __restrict__ Wcu, float* __restrict__ Wcv,
             float* __restrict__ bu, float* __restrict__ bv)
{
    __shared__ float wrow[256];
    const int r = blockIdx.x, isv = blockIdx.y;
    const float* W = isv ? Wn1 : Wr1;
    const int k = threadIdx.x;
    wrow[k] = W[(size_t)r * 387 + 131 + k];
    __syncthreads();
    float acc = 0.f;
    for (int o = 0; o < 256; ++o) acc += wrow[o] * Wl2[(size_t)o * 256 + k];
    (isv ? Wcv : Wcu)[(size_t)r * 256 + k] = acc;
    if (k == 0) {
        float s = 0.f;
        for (int o = 0; o < 256; ++o) s += wrow[o] * bl2[o];
        if (isv) bv[r] = s; else bu[r] = b1[r] + s;
    }
}

// ---------------------------------------------------------------------------
// KNN (K=3), branchless. LDS: float4 (x,y,z,|p|^2) per point (64 KB).
// 32 queries x 8 scanners per block; 1 ds_read_b128 + ~7 VALU per candidate;
// lexicographic (d, idx) semantics identical to the verified R6/R9 version.
// ---------------------------------------------------------------------------
__global__ __launch_bounds__(TPB)
void knn_k(const float* __restrict__ loc, int* __restrict__ idxp)
{
    __shared__ float4 pt[NPTS];   // 64 KB
    const int b = blockIdx.y;
    const float* L = loc + (size_t)b * 3 * NPTS;
    for (int j = threadIdx.x; j < NPTS; j += TPB) {
        float x = L[j], y = L[NPTS + j], z = L[2 * NPTS + j];
        float sq;
        {
            #pragma clang fp contract(off)
            sq = x * x + y * y + z * z;
        }
        pt[j] = make_float4(x, y, z, sq);
    }
    __syncthreads();

    const int ql = threadIdx.x >> 3;
    const int s  = threadIdx.x & 7;
    const int i  = blockIdx.x * 32 + ql;

    const float4 q = pt[i];
    const float xi = q.x, yi = q.y, zi = q.z, sqi = q.w;

    float d0 = 3e38f, d1 = 3e38f, d2 = 3e38f;
    int   i0 = 0x7fffffff, i1 = 0x7fffffff, i2 = 0x7fffffff;

    #pragma unroll 4
    for (int k = 0; k < NPTS / 8; ++k) {
        const int j = (k << 3) | s;
        const float4 p = pt[j];
        float d;
        {
            #pragma clang fp contract(off)
            float dot = xi * p.x + yi * p.y + zi * p.z;
            d = (sqi + p.w) - 2.0f * dot;
        }
        const bool valid = (j != i);
        const bool lt2 = valid && (d < d2 || (d == d2 && j < i2));
        const bool lt1 = valid && (d < d1 || (d == d1 && j < i1));
        const bool lt0 = valid && (d < d0 || (d == d0 && j < i0));
        d2 = lt1 ? d1 : (lt2 ? d : d2);  i2 = lt1 ? i1 : (lt2 ? j : i2);
        d1 = lt0 ? d0 : (lt1 ? d : d1);  i1 = lt0 ? i0 : (lt1 ? j : i1);
        d0 = lt0 ? d  : d0;              i0 = lt0 ? j  : i0;
    }

    // butterfly merge across the 8 scanners of each query (branchless)
    #pragma unroll
    for (int m = 1; m <= 4; m <<= 1) {
        float e0 = __shfl_xor(d0, m), e1 = __shfl_xor(d1, m), e2 = __shfl_xor(d2, m);
        int   j0 = __shfl_xor(i0, m), j1 = __shfl_xor(i1, m), j2 = __shfl_xor(i2, m);
        float ee[3] = {e0, e1, e2};
        int   jj[3] = {j0, j1, j2};
        #pragma unroll
        for (int t = 0; t < 3; ++t) {
            const float e = ee[t]; const int je = jj[t];
            const bool lt2 = (e < d2 || (e == d2 && je < i2));
            const bool lt1 = (e < d1 || (e == d1 && je < i1));
            const bool lt0 = (e < d0 || (e == d0 && je < i0));
            d2 = lt1 ? d1 : (lt2 ? e : d2);  i2 = lt1 ? i1 : (lt2 ? je : i2);
            d1 = lt0 ? d0 : (lt1 ? e : d1);  i1 = lt0 ? i0 : (lt1 ? je : i1);
            d0 = lt0 ? e  : d0;              i0 = lt0 ? je : i0;
        }
    }

    if (s == 0) {
        idxp[0 * BN + b * NPTS + i] = i0;
        idxp[1 * BN + b * NPTS + i] = i1;
        idxp[2 * BN + b * NPTS + i] = i2;
    }
}

// ---------------------------------------------------------------------------
__global__ __launch_bounds__(TPB)
void gridconv_k(const float* __restrict__ loc, const float* __restrict__ h2,
                const float* __restrict__ Wg, const float* __restrict__ bg,
                float* __restrict__ gridv)
{
    const int n = blockIdx.x * TPB + threadIdx.x;
    const int b = blockIdx.y;
    float a0 = bg[0], a1 = bg[1];
    #pragma unroll
    for (int c = 0; c < 3; ++c) {
        float v = loc[((size_t)b * 3 + c) * NPTS + n];
        a0 += Wg[c] * v; a1 += Wg[67 + c] * v;
    }
    const float* hp = h2 + (size_t)b * 64 * NPTS + n;
    #pragma unroll 4
    for (int c = 0; c < 64; ++c) {
        float v = hp[(size_t)c * NPTS];
        a0 += Wg[3 + c] * v; a1 += Wg[70 + c] * v;
    }
    gridv[((size_t)b * 2 + 0) * NPTS + n] = a0;
    gridv[((size_t)b * 2 + 1) * NPTS + n] = a1;
}

// ---------------------------------------------------------------------------
// grid_sample -> bf16 pooled [c][b*NPTS+n]  (coalesced bf16 writes)
// ---------------------------------------------------------------------------
__global__ __launch_bounds__(TPB)
void gridsample_bf_k(const float* __restrict__ gridv, const float* __restrict__ p0,
                     const float* __restrict__ p1, const float* __restrict__ p2,
                     __hip_bfloat16* __restrict__ pooledbf)
{
    const int n    = blockIdx.x * 64 + (threadIdx.x & 63);
    const int cidx = blockIdx.y * 4 + (threadIdx.x >> 6);
    const int b    = blockIdx.z;
    const float* img; int C, H, c;
    if (cidx < 64)       { img = p0; C = 64;  H = 112; c = cidx; }
    else if (cidx < 192) { img = p1; C = 128; H = 56;  c = cidx - 64; }
    else                 { img = p2; C = 256; H = 28;  c = cidx - 192; }
    const float gx = gridv[((size_t)b * 2 + 0) * NPTS + n];
    const float gy = gridv[((size_t)b * 2 + 1) * NPTS + n];
    float wx, wy; int x0, x1, y0, y1;
    {
        #pragma clang fp contract(off)
        float ix  = ((gx + 1.0f) * (float)H - 1.0f) * 0.5f;
        float iy  = ((gy + 1.0f) * (float)H - 1.0f) * 0.5f;
        float ix0 = floorf(ix), iy0 = floorf(iy);
        wx = ix - ix0; wy = iy - iy0;
        x0 = min(max((int)ix0, 0),     H - 1);
        x1 = min(max((int)ix0 + 1, 0), H - 1);
        y0 = min(max((int)iy0, 0),     H - 1);
        y1 = min(max((int)iy0 + 1, 0), H - 1);
    }
    const float* pl = img + ((size_t)b * C + c) * H * H;
    float v = pl[y0*H + x0] * (1.f-wx)*(1.f-wy) + pl[y0*H + x1] * wx*(1.f-wy)
            + pl[y1*H + x0] * (1.f-wx)*wy       + pl[y1*H + x1] * wx*wy;
    pooledbf[(size_t)cidx * BN + b * NPTS + n] = __float2bfloat16(v);
}

// ---------------------------------------------------------------------------
// feat = relu(u + v[j0]+v[j1]+v[j2]) -> bf16 into next concat buffer rows 3+
// uv: f32 [512][BN], u = rows 0-255, v = rows 256-511
// ---------------------------------------------------------------------------
__global__ __launch_bounds__(TPB)
void gatherfuse_bf_k(const float* __restrict__ uv, const int* __restrict__ idxp,
                     __hip_bfloat16* __restrict__ Xc)
{
    const int n = blockIdx.x * TPB + threadIdx.x;
    const int c = blockIdx.y;
    const int b = blockIdx.z;
    const int j0 = idxp[0 * BN + b * NPTS + n] & (NPTS - 1);
    const int j1 = idxp[1 * BN + b * NPTS + n] & (NPTS - 1);
    const int j2 = idxp[2 * BN + b * NPTS + n] & (NPTS - 1);
    const float* u = uv + (size_t)c * BN + b * NPTS;
    const float* v = uv + (size_t)(256 + c) * BN + b * NPTS;
    float r = u[n] + v[j0] + v[j1] + v[j2];
    Xc[(size_t)(3 + c) * BN + b * NPTS + n] = __float2bfloat16(fmaxf(r, 0.f));
}

// ---------------------------------------------------------------------------
// layer-3 gather + Wloc head. uv: u3 = rows 0-127, v3 = rows 128-255 (f32).
// ---------------------------------------------------------------------------
__global__ __launch_bounds__(TPB)
void finalfuse_k(const float* __restrict__ uv, const int* __restrict__ idxp,
                 const float* __restrict__ loc,
                 const float* __restrict__ Wloc, const float* __restrict__ bloc,
                 float* __restrict__ outloc, float* __restrict__ outfeat)
{
    __shared__ float wl[393];
    for (int idx = threadIdx.x; idx < 393; idx += TPB) wl[idx] = Wloc[idx];
    __syncthreads();
    const int n = blockIdx.x * TPB + threadIdx.x;
    const int b = blockIdx.y;
    const int j0 = idxp[0 * BN + b * NPTS + n] & (NPTS - 1);
    const int j1 = idxp[1 * BN + b * NPTS + n] & (NPTS - 1);
    const int j2 = idxp[2 * BN + b * NPTS + n] & (NPTS - 1);
    float a0 = bloc[0], a1 = bloc[1], a2 = bloc[2];
    float l[3];
    #pragma unroll
    for (int c = 0; c < 3; ++c) {
        float v = loc[((size_t)b * 3 + c) * NPTS + n];
        l[c] = v;
        a0 += wl[c] * v; a1 += wl[131 + c] * v; a2 += wl[262 + c] * v;
    }
    #pragma unroll 4
    for (int c = 0; c < 128; ++c) {
        const float* u = uv + (size_t)c * BN + b * NPTS;
        const float* v = uv + (size_t)(128 + c) * BN + b * NPTS;
        float f = fmaxf(u[n] + v[j0] + v[j1] + v[j2], 0.f);
        outfeat[((size_t)b * 128 + c) * NPTS + n] = f;
        a0 += wl[3 + c] * f; a1 += wl[134 + c] * f; a2 += wl[265 + c] * f;
    }
    outloc[((size_t)b * 3 + 0) * NPTS + n] = l[0] + tanhf(a0);
    outloc[((size_t)b * 3 + 1) * NPTS + n] = l[1] + tanhf(a1);
    outloc[((size_t)b * 3 + 2) * NPTS + n] = l[2] + tanhf(a2);
}

// ---------------------------------------------------------------------------
__global__ __launch_bounds__(TPB)
void castrows_k(const float* __restrict__ src, __hip_bfloat16* __restrict__ dst,
                int C, int rowOff)
{
    const int n = blockIdx.x * TPB + threadIdx.x;
    const int c = blockIdx.y, b = blockIdx.z;
    dst[(size_t)(rowOff + c) * BN + b * NPTS + n] =
        __float2bfloat16(src[((size_t)b * C + c) * NPTS + n]);
}

__global__ __launch_bounds__(TPB)
void zerobf_k(__hip_bfloat16* __restrict__ dst, int count16B)
{
    int i = blockIdx.x * TPB + threadIdx.x;
    if (i < count16B) ((int4*)dst)[i] = make_int4(0, 0, 0, 0);
}

__global__ __launch_bounds__(TPB)
void wassemble_k(const float* __restrict__ S1, int ld1, int c1,
                 const float* __restrict__ S2, int ld2, int c2,
                 int Kp, __hip_bfloat16* __restrict__ dst)
{
    const int c = blockIdx.x * TPB + threadIdx.x;
    const int r = blockIdx.y;
    if (c >= Kp) return;
    float v = 0.f;
    if (c < c1) v = S1[(size_t)r * ld1 + c];
    else if (c < c1 + c2) v = S2[(size_t)r * ld2 + (c - c1)];
    dst[(size_t)r * Kp + c] = __float2bfloat16(v);
}

__global__ __launch_bounds__(TPB)
void biasfill_k(const float* __restrict__ b2, const float* __restrict__ b3,
                float* __restrict__ bias3, float* __restrict__ bias4)
{
    int i = blockIdx.x * TPB + threadIdx.x;
    if (i < 512) bias3[i] = (i < 256) ? b2[i] : 0.f;
    else if (i < 768) { int j = i - 512; bias4[j] = (j < 128) ? b3[j] : 0.f; }
}

__global__ __launch_bounds__(TPB)
void sentinel_k(float* __restrict__ out, int ntot, float c)
{
    int i = blockIdx.x * TPB + threadIdx.x;
    if (i < ntot) out[i] = c;
}

// ---------------------------------------------------------------------------
extern "C" void kernel_launch(void* const* d_in, const int* in_sizes, int n_in,
                              void* d_out, int out_size, void* d_ws, size_t ws_size,
                              hipStream_t stream)
{
    static const int EXP_INS[26] = {
        49152, 2097152, 3211264, 1605632, 802816,
        8384, 64, 4096, 64, 134, 2,
        114688, 256, 65536, 256,
        99072, 99072, 256, 66304, 66304, 256,
        33152, 33152, 128, 393, 3 };
    constexpr size_t WS_REQ = 16237824ull * 4ull;   // 64.95 MB (proven OK)

    float code = -1.f;
    if (n_in != 26) code = 64.f;
    else {
        bool ok = true;
        for (int i = 0; i < 26; ++i) ok = ok && (in_sizes[i] == EXP_INS[i]);
        if (!ok) code = 24.f;
    }
    if (code < 0.f && out_size != 2146304) code = 32.f;
    if (code < 0.f && ws_size < WS_REQ)    code = 16.f;
    if (code >= 0.f) {
        sentinel_k<<<dim3((out_size + TPB - 1) / TPB), dim3(TPB), 0, stream>>>(
            (float*)d_out, out_size, code);
        return;
    }

    const float* x_loc  = (const float*)d_in[0];
    const float* x_feat = (const float*)d_in[1];
    const float* p0     = (const float*)d_in[2];
    const float* p1     = (const float*)d_in[3];
    const float* p2     = (const float*)d_in[4];
    const float* Ws1 = (const float*)d_in[5];  const float* bs1 = (const float*)d_in[6];
    const float* Ws2 = (const float*)d_in[7];  const float* bs2 = (const float*)d_in[8];
    const float* Wg  = (const float*)d_in[9];  const float* bg  = (const float*)d_in[10];
    const float* Wl1 = (const float*)d_in[11]; const float* bl1 = (const float*)d_in[12];
    const float* Wl2 = (const float*)d_in[13]; const float* bl2 = (const float*)d_in[14];
    const float* Wr1 = (const float*)d_in[15]; const float* Wn1 = (const float*)d_in[16];
    const float* b1  = (const float*)d_in[17];
    const float* Wr2 = (const float*)d_in[18]; const float* Wn2 = (const float*)d_in[19];
    const float* b2  = (const float*)d_in[20];
    const float* Wr3 = (const float*)d_in[21]; const float* Wn3 = (const float*)d_in[22];
    const float* b3  = (const float*)d_in[23];
    const float* Wloc= (const float*)d_in[24]; const float* bloc= (const float*)d_in[25];

    float* ws = (float*)d_ws;
    // region U: uv f32 [512][BN]; hosts h1/h2 early
    float* U  = ws;                       // 8,388,608 f
    float* h1 = U;
    float* h2 = U + 1048576;
    // region P (bf16): pooledbf [448][BN] -> later Xc2 [320][BN]
    __hip_bfloat16* pooledbf = (__hip_bfloat16*)(ws + 8388608);   // 3,670,016 f
    __hip_bfloat16* Xc2      = pooledbf;
    // region X1 (bf16): Xc1 [448][BN] -> later Xc3 [320][BN]
    __hip_bfloat16* Xc1 = (__hip_bfloat16*)(ws + 12058624);       // 3,670,016 f
    __hip_bfloat16* Xc3 = Xc1;
    // small region
    float* S     = ws + 15728640;
    float* gridv = S;                       // 32,768
    int*   idxp  = (int*)(S + 32768);       // 49,152
    float* Wc1u  = S + 81920;               // 65,536
    float* Wc1v  = S + 147456;              // 65,536
    float* bu1   = S + 212992;              // 256
    float* bv1   = S + 213248;              // 256 (contiguous with bu1)
    float* bias3 = S + 213504;              // 512
    float* bias4 = S + 214016;              // 256
    __hip_bfloat16* Wb1 = (__hip_bfloat16*)(S + 214272);  // 256x448
    __hip_bfloat16* Wb2 = (__hip_bfloat16*)(S + 271616);  // 512x448
    __hip_bfloat16* Wb3 = (__hip_bfloat16*)(S + 386304);  // 512x320
    __hip_bfloat16* Wb4 = (__hip_bfloat16*)(S + 468224);  // 256x320
    // total = 16,237,824 floats

    float* out_loc  = (float*)d_out;
    float* out_feat = out_loc + (size_t)BATCH * 3 * NPTS;

    dim3 blk(TPB);
    const int GX = NPTS / TPB;   // 16
    Seg z{nullptr, nullptr, 0, 0};
    const int ZPAD16 = 61 * BN / 8;   // 16B chunks in 61 zero rows

    // weight prep
    wcomp_k<<<dim3(256, 2), blk, 0, stream>>>(Wr1, Wn1, Wl2, bl2, b1,
                                              Wc1u, Wc1v, bu1, bv1);
    biasfill_k<<<dim3(3), blk, 0, stream>>>(b2, b3, bias3, bias4);
    wassemble_k<<<dim3(2, 256), blk, 0, stream>>>(Wl1, 448, 448, nullptr, 0, 0, 448, Wb1);
    wassemble_k<<<dim3(2, 256), blk, 0, stream>>>(Wr1, 387, 131, Wc1u, 256, 256, 448, Wb2);
    wassemble_k<<<dim3(2, 256), blk, 0, stream>>>(Wn1, 387, 131, Wc1v, 256, 256, 448, Wb2 + 256*448);
    wassemble_k<<<dim3(2, 256), blk, 0, stream>>>(Wr2, 259, 259, nullptr, 0, 0, 320, Wb3);
    wassemble_k<<<dim3(2, 256), blk, 0, stream>>>(Wn2, 259, 259, nullptr, 0, 0, 320, Wb3 + 256*320);
    wassemble_k<<<dim3(2, 128), blk, 0, stream>>>(Wr3, 259, 259, nullptr, 0, 0, 320, Wb4);
    wassemble_k<<<dim3(2, 128), blk, 0, stream>>>(Wn3, 259, 259, nullptr, 0, 0, 320, Wb4 + 128*320);

    // front-end (f32)
    conv1x1_k<true><<<dim3(GX, 4, BATCH), blk, 0, stream>>>(
        Seg{x_loc, Ws1, 3, 131}, Seg{x_feat, Ws1 + 3, 128, 131}, 2, 131, bs1, h1, 64);
    conv1x1_k<true><<<dim3(GX, 4, BATCH), blk, 0, stream>>>(
        Seg{h1, Ws2, 64, 64}, z, 1, 64, bs2, h2, 64);
    gridconv_k<<<dim3(GX, BATCH), blk, 0, stream>>>(x_loc, h2, Wg, bg, gridv);
    knn_k<<<dim3(NPTS / 32, BATCH), blk, 0, stream>>>(x_loc, idxp);
    gridsample_bf_k<<<dim3(NPTS / 64, 112, BATCH), blk, 0, stream>>>(
        gridv, p0, p1, p2, pooledbf);

    // Xc1 = [loc; x_feat; t; 0-pad]
    castrows_k<<<dim3(GX, 3, BATCH), blk, 0, stream>>>(x_loc, Xc1, 3, 0);
    castrows_k<<<dim3(GX, 128, BATCH), blk, 0, stream>>>(x_feat, Xc1, 128, 3);
    zerobf_k<<<dim3((ZPAD16 + TPB - 1) / TPB), blk, 0, stream>>>(Xc1 + (size_t)387 * BN, ZPAD16);
    // G1: t = relu(Wl1@pooled + bl1) -> Xc1 rows 131+
    gemm_k<1><<<dim3(128, 2), blk, 0, stream>>>(Wb1, pooledbf, bl1, nullptr, Xc1, 448, 131);

    // Xc2 setup (region reuse: after G1 consumed pooledbf)
    castrows_k<<<dim3(GX, 3, BATCH), blk, 0, stream>>>(x_loc, Xc2, 3, 0);
    zerobf_k<<<dim3((ZPAD16 + TPB - 1) / TPB), blk, 0, stream>>>(Xc2 + (size_t)259 * BN, ZPAD16);
    // G2: [u1; v1] = Wb2 @ Xc1 + [bu1; bv1]
    gemm_k<0><<<dim3(128, 4), blk, 0, stream>>>(Wb2, Xc1, bu1, U, nullptr, 448, 0);
    gatherfuse_bf_k<<<dim3(GX, 256, BATCH), blk, 0, stream>>>(U, idxp, Xc2);

    // Xc3 setup (region reuse: after G2 consumed Xc1)
    castrows_k<<<dim3(GX, 3, BATCH), blk, 0, stream>>>(x_loc, Xc3, 3, 0);
    zerobf_k<<<dim3((ZPAD16 + TPB - 1) / TPB), blk, 0, stream>>>(Xc3 + (size_t)259 * BN, ZPAD16);
    // G3: [u2; v2] = Wb3 @ Xc2 + [b2; 0]
    gemm_k<0><<<dim3(128, 4), blk, 0, stream>>>(Wb3, Xc2, bias3, U, nullptr, 320, 0);
    gatherfuse_bf_k<<<dim3(GX, 256, BATCH), blk, 0, stream>>>(U, idxp, Xc3);

    // G4: [u3; v3] = Wb4 @ Xc3 + [b3; 0]
    gemm_k<0><<<dim3(128, 2), blk, 0, stream>>>(Wb4, Xc3, bias4, U, nullptr, 320, 0);
    finalfuse_k<<<dim3(GX, BATCH), blk, 0, stream>>>(
        U, idxp, x_loc, Wloc, bloc, out_loc, out_feat);
}

// Round 11
// 421.312 us; speedup vs baseline: 1.0029x; 1.0029x over previous
//
#include <hip/hip_runtime.h>
#include <hip/hip_bf16.h>

#define TPB 256
static constexpr int BATCH = 4;
static constexpr int NPTS  = 4096;
static constexpr int BN    = BATCH * NPTS;   // 16384 columns for all GEMMs

typedef __attribute__((ext_vector_type(8))) short short8v;
typedef __attribute__((ext_vector_type(4))) short short4v;
typedef __attribute__((ext_vector_type(4))) float f32x4;

struct Seg { const float* in; const float* W; int C; int ws; };

__device__ __forceinline__ void gload16(const void* g, void* l) {
    __builtin_amdgcn_global_load_lds(
        (const __attribute__((address_space(1))) void*)g,
        (__attribute__((address_space(3))) void*)l, 16, 0, 0);
}

// ---------------------------------------------------------------------------
// MFMA GEMM: D[m][col] = bias[m] + sum_k A[m][k]*B[k][col]
//   A: bf16 [M][Kp] row-major (Kp % 64 == 0), B: bf16 [Kp][BN] row-major.
// Block 256 thr = 4 waves; tile 128x128, BK=64; wave quadrant 64x64 (4x4 frags).
// A-tile: global_load_lds, source-address XOR swizzle, LDS [row][64k] 128B rows.
// B-tile: reg-staged (2x global dwordx4: 8 cols x k-pair) -> ds_write_b32 into
//   k-contiguous LDS [col][64k] with 136B row stride (conflict-free reads).
// Both fragments use slot->k map mu(g4,e)=g4*4+(e&3)+16*(e>>2) (same map on A
// and B => result independent of the HW k-permutation; mu bijective on [0,32)).
// No inline asm: __syncthreads() drains vmcnt (global_load_lds) + lgkmcnt.
// EPI 0: f32 out (+bias). EPI 1: bf16 out (+bias+relu) at row offset rowOff.
// ---------------------------------------------------------------------------
template<int EPI>
__global__ __launch_bounds__(256)
void gemm_k(const __hip_bfloat16* __restrict__ A, const __hip_bfloat16* __restrict__ B,
            const float* __restrict__ bias, float* __restrict__ outF,
            __hip_bfloat16* __restrict__ outB, int Kp, int rowOff)
{
    __shared__ short Alds[8192];   // 128 rows x 64 k (16 KB), 128B rows
    __shared__ short Blds[8704];   // 128 cols x 68 shorts (136B rows, 17 KB)
    const int tid = threadIdx.x, lane = tid & 63, wid = tid >> 6;
    const int wm = wid & 1, wn = wid >> 1;
    const int n0 = blockIdx.x * 128, m0 = blockIdx.y * 128;

    // ---- A staging setup: 1024 granules of 16B, 4 per thread (gload16) ----
    const char* asrc[4]; short* adst[4];
    #pragma unroll
    for (int t = 0; t < 4; ++t) {
        const int g = (wid * 4 + t) * 64 + lane;
        const int arow = g >> 3, ai = g & 7;
        asrc[t] = (const char*)A +
                  (((size_t)(m0 + arow)) * Kp + ((ai ^ (arow & 7)) << 3)) * 2;
        adst[t] = &Alds[(wid * 4 + t) * 512];   // wave-uniform base; HW adds lane*16
    }
    // ---- B staging setup: item q = it*256+tid -> kp = q>>4 (k-pair), c8 = q&15
    const char* bsrc[2]; int bkp[2], bc0[2];
    #pragma unroll
    for (int it = 0; it < 2; ++it) {
        const int q = it * 256 + tid;
        bkp[it] = q >> 4;          // k-pair index 0..31 (k = 2*kp, 2*kp+1)
        bc0[it] = (q & 15) * 8;    // first of 8 columns
        bsrc[it] = (const char*)B +
                   (((size_t)(bkp[it] * 2)) * BN + (n0 + bc0[it])) * 2;
    }

    f32x4 acc[4][4];
    #pragma unroll
    for (int i = 0; i < 4; ++i)
        #pragma unroll
        for (int j = 0; j < 4; ++j) acc[i][j] = (f32x4){0.f, 0.f, 0.f, 0.f};

    const int rl = lane & 15, g4 = lane >> 4;

    const int nkt = Kp >> 6;
    for (int kt = 0; kt < nkt; ++kt) {
        __syncthreads();   // previous iteration's LDS reads complete

        // B: load 8 cols x (k, k+1) into regs (coalesced 16B loads)
        short8v blo[2], bhi[2];
        #pragma unroll
        for (int it = 0; it < 2; ++it) {
            blo[it] = *(const short8v*)(bsrc[it]);
            bhi[it] = *(const short8v*)(bsrc[it] + (size_t)BN * 2);
            bsrc[it] += (size_t)64 * BN * 2;   // advance 64 k-rows
        }
        // A: async global->LDS
        #pragma unroll
        for (int t = 0; t < 4; ++t) {
            gload16(asrc[t], adst[t]);
            asrc[t] += 128;                    // +64 k
        }
        // B: transpose into LDS [col][k] via ds_write_b32 (k-pairs)
        #pragma unroll
        for (int it = 0; it < 2; ++it) {
            #pragma unroll
            for (int j = 0; j < 8; ++j) {
                const int c = bc0[it] + j;
                const int val = ((int)(unsigned short)blo[it][j]) |
                                (((int)(unsigned short)bhi[it][j]) << 16);
                *(int*)((char*)Blds + c * 136 + bkp[it] * 4) = val;
            }
        }
        __syncthreads();   // drains vmcnt(gload_lds) + lgkmcnt(ds_write) + barrier

        #pragma unroll
        for (int ks = 0; ks < 2; ++ks) {
            // A fragments (XOR-swizzled rows)
            short8v af[4];
            #pragma unroll
            for (int mf = 0; mf < 4; ++mf) {
                const int row = wm * 64 + mf * 16 + rl;
                const int base = row * 128, sw = (row & 7) << 4;
                const short4v lo = *(const short4v*)((const char*)Alds +
                                    (base + ((ks * 64 + (g4 << 3)) ^ sw)));
                const short4v hi = *(const short4v*)((const char*)Alds +
                                    (base + ((ks * 64 + (g4 << 3) + 32) ^ sw)));
                af[mf] = __builtin_shufflevector(lo, hi, 0,1,2,3,4,5,6,7);
            }
            // B fragments (linear 136B-stride rows; conflict-free)
            short8v bfv[4];
            #pragma unroll
            for (int nf = 0; nf < 4; ++nf) {
                const int colr = wn * 64 + nf * 16 + rl;
                const char* bp = (const char*)Blds + colr * 136 + ks * 64 + (g4 << 3);
                const short4v lo = *(const short4v*)bp;
                const short4v hi = *(const short4v*)(bp + 32);
                bfv[nf] = __builtin_shufflevector(lo, hi, 0,1,2,3,4,5,6,7);
            }
            #pragma unroll
            for (int mf = 0; mf < 4; ++mf)
                #pragma unroll
                for (int nf = 0; nf < 4; ++nf)
                    acc[mf][nf] = __builtin_amdgcn_mfma_f32_16x16x32_bf16(
                        af[mf], bfv[nf], acc[mf][nf], 0, 0, 0);
        }
    }

    #pragma unroll
    for (int mf = 0; mf < 4; ++mf) {
        #pragma unroll
        for (int i = 0; i < 4; ++i) {
            const int row = m0 + wm * 64 + mf * 16 + g4 * 4 + i;
            const float bs = bias[row];
            #pragma unroll
            for (int nf = 0; nf < 4; ++nf) {
                const int col = n0 + wn * 64 + nf * 16 + rl;
                float v = acc[mf][nf][i] + bs;
                if (EPI == 1) {
                    v = fmaxf(v, 0.f);
                    outB[(size_t)(rowOff + row) * BN + col] = __float2bfloat16(v);
                } else {
                    outF[(size_t)row * BN + col] = v;
                }
            }
        }
    }
}

// ---------------------------------------------------------------------------
// small f32 conv (kept for h1/h2 only)
// ---------------------------------------------------------------------------
template<bool RELU>
__global__ __launch_bounds__(TPB)
void conv1x1_k(Seg s0, Seg s1, int nseg, int Ctot,
               const float* __restrict__ bias, float* __restrict__ out, int O)
{
    __shared__ float Wl[131][16];
    const int n  = blockIdx.x * TPB + threadIdx.x;
    const int o0 = blockIdx.y * 16;
    const int b  = blockIdx.z;
    Seg segs[2] = {s0, s1};
    int off[3]; off[0] = 0;
    #pragma unroll
    for (int k = 0; k < 2; ++k) off[k + 1] = off[k] + (k < nseg ? segs[k].C : 0);
    for (int idx = threadIdx.x; idx < Ctot * 16; idx += TPB) {
        int c = idx >> 4, t = idx & 15;
        int k = (nseg > 1 && c >= off[1]) ? 1 : 0;
        Wl[c][t] = segs[k].W[(size_t)(o0 + t) * segs[k].ws + (c - off[k])];
    }
    __syncthreads();
    float acc[16];
    #pragma unroll
    for (int t = 0; t < 16; ++t) acc[t] = 0.f;
    int cbase = 0;
    for (int k = 0; k < nseg; ++k) {
        const float* ip = segs[k].in + (size_t)b * segs[k].C * NPTS + n;
        const int C = segs[k].C;
        #pragma unroll 4
        for (int cc = 0; cc < C; ++cc) {
            float v = ip[(size_t)cc * NPTS];
            const float4* wr = (const float4*)(&Wl[cbase + cc][0]);
            #pragma unroll
            for (int q = 0; q < 4; ++q) {
                float4 w = wr[q];
                acc[4*q+0] += w.x * v; acc[4*q+1] += w.y * v;
                acc[4*q+2] += w.z * v; acc[4*q+3] += w.w * v;
            }
        }
        cbase += C;
    }
    #pragma unroll
    for (int t = 0; t < 16; ++t) {
        float r = acc[t] + bias[o0 + t];
        if (RELU) r = fmaxf(r, 0.f);
        out[((size_t)b * O + o0 + t) * NPTS + n] = r;
    }
}

// ---------------------------------------------------------------------------
__global__ __launch_bounds__(TPB)
void wcomp_k(const float* __restrict__ Wr1, const float* __restrict__ Wn1,
             const float* __restrict__ Wl2, const float* __restrict__ bl2,
             const float* __restrict__ b1,
             float* __restrict__ Wcu, float* __restrict__ Wcv,
             float* __restrict__ bu, float* __restrict__ bv)
{
    __shared__ float wrow[256];
    const int r = blockIdx.x, isv = blockIdx.y;
    const float* W = isv ? Wn1 : Wr1;
    const int k = threadIdx.x;
    wrow[k] = W[(size_t)r * 387 + 131 + k];
    __syncthreads();
    float acc = 0.f;
    for (int o = 0; o < 256; ++o) acc += wrow[o] * Wl2[(size_t)o * 256 + k];
    (isv ? Wcv : Wcu)[(size_t)r * 256 + k] = acc;
    if (k == 0) {
        float s = 0.f;
        for (int o = 0; o < 256; ++o) s += wrow[o] * bl2[o];
        if (isv) bv[r] = s; else bu[r] = b1[r] + s;
    }
}

// ---------------------------------------------------------------------------
// KNN (K=3), branchless. LDS: 3 fp32 arrays (48 KB) -> 3 blocks/CU.
// Block = 16 queries x 16 scanners (256 thr); grid (NPTS/16, BATCH) = 1024
// blocks (4 blocks/CU of work). Per wave: 16 consecutive-word LDS reads
// broadcast x4 lanes (conflict-free). Lexicographic (d, idx) semantics
// identical to the verified R6/R9 chain.
// ---------------------------------------------------------------------------
__global__ __launch_bounds__(TPB)
void knn_k(const float* __restrict__ loc, int* __restrict__ idxp)
{
    __shared__ float lx[NPTS], ly[NPTS], lz[NPTS];   // 48 KB
    const int b = blockIdx.y;
    const float* L = loc + (size_t)b * 3 * NPTS;
    for (int j = threadIdx.x; j < NPTS; j += TPB) {
        lx[j] = L[j]; ly[j] = L[NPTS + j]; lz[j] = L[2 * NPTS + j];
    }
    __syncthreads();

    const int ql = threadIdx.x >> 4;     // 16 queries per block
    const int s  = threadIdx.x & 15;     // 16 scanners per query
    const int i  = blockIdx.x * 16 + ql;

    const float xi = lx[i], yi = ly[i], zi = lz[i];
    float sqi;
    {
        #pragma clang fp contract(off)
        sqi = xi * xi + yi * yi + zi * zi;
    }

    float d0 = 3e38f, d1 = 3e38f, d2 = 3e38f;
    int   i0 = 0x7fffffff, i1 = 0x7fffffff, i2 = 0x7fffffff;

    #pragma unroll 4
    for (int k = 0; k < NPTS / 16; ++k) {
        const int j = (k << 4) | s;
        const float xj = lx[j], yj = ly[j], zj = lz[j];
        float d;
        {
            #pragma clang fp contract(off)
            float sqj = xj * xj + yj * yj + zj * zj;
            float dot = xi * xj + yi * yj + zi * zj;
            d = (sqi + sqj) - 2.0f * dot;
        }
        const bool valid = (j != i);
        const bool lt2 = valid && (d < d2 || (d == d2 && j < i2));
        const bool lt1 = valid && (d < d1 || (d == d1 && j < i1));
        const bool lt0 = valid && (d < d0 || (d == d0 && j < i0));
        d2 = lt1 ? d1 : (lt2 ? d : d2);  i2 = lt1 ? i1 : (lt2 ? j : i2);
        d1 = lt0 ? d0 : (lt1 ? d : d1);  i1 = lt0 ? i0 : (lt1 ? j : i1);
        d0 = lt0 ? d  : d0;              i0 = lt0 ? j  : i0;
    }

    // butterfly merge across the 16 scanners of each query (branchless)
    #pragma unroll
    for (int m = 1; m <= 8; m <<= 1) {
        float e0 = __shfl_xor(d0, m), e1 = __shfl_xor(d1, m), e2 = __shfl_xor(d2, m);
        int   j0 = __shfl_xor(i0, m), j1 = __shfl_xor(i1, m), j2 = __shfl_xor(i2, m);
        float ee[3] = {e0, e1, e2};
        int   jj[3] = {j0, j1, j2};
        #pragma unroll
        for (int t = 0; t < 3; ++t) {
            const float e = ee[t]; const int je = jj[t];
            const bool lt2 = (e < d2 || (e == d2 && je < i2));
            const bool lt1 = (e < d1 || (e == d1 && je < i1));
            const bool lt0 = (e < d0 || (e == d0 && je < i0));
            d2 = lt1 ? d1 : (lt2 ? e : d2);  i2 = lt1 ? i1 : (lt2 ? je : i2);
            d1 = lt0 ? d0 : (lt1 ? e : d1);  i1 = lt0 ? i0 : (lt1 ? je : i1);
            d0 = lt0 ? e  : d0;              i0 = lt0 ? je : i0;
        }
    }

    if (s == 0) {
        idxp[0 * BN + b * NPTS + i] = i0;
        idxp[1 * BN + b * NPTS + i] = i1;
        idxp[2 * BN + b * NPTS + i] = i2;
    }
}

// ---------------------------------------------------------------------------
__global__ __launch_bounds__(TPB)
void gridconv_k(const float* __restrict__ loc, const float* __restrict__ h2,
                const float* __restrict__ Wg, const float* __restrict__ bg,
                float* __restrict__ gridv)
{
    const int n = blockIdx.x * TPB + threadIdx.x;
    const int b = blockIdx.y;
    float a0 = bg[0], a1 = bg[1];
    #pragma unroll
    for (int c = 0; c < 3; ++c) {
        float v = loc[((size_t)b * 3 + c) * NPTS + n];
        a0 += Wg[c] * v; a1 += Wg[67 + c] * v;
    }
    const float* hp = h2 + (size_t)b * 64 * NPTS + n;
    #pragma unroll 4
    for (int c = 0; c < 64; ++c) {
        float v = hp[(size_t)c * NPTS];
        a0 += Wg[3 + c] * v; a1 += Wg[70 + c] * v;
    }
    gridv[((size_t)b * 2 + 0) * NPTS + n] = a0;
    gridv[((size_t)b * 2 + 1) * NPTS + n] = a1;
}

// ---------------------------------------------------------------------------
// grid_sample -> bf16 pooled [c][b*NPTS+n]  (coalesced bf16 writes)
// ---------------------------------------------------------------------------
__global__ __launch_bounds__(TPB)
void gridsample_bf_k(const float* __restrict__ gridv, const float* __restrict__ p0,
                     const float* __restrict__ p1, const float* __restrict__ p2,
                     __hip_bfloat16* __restrict__ pooledbf)
{
    const int n    = blockIdx.x * 64 + (threadIdx.x & 63);
    const int cidx = blockIdx.y * 4 + (threadIdx.x >> 6);
    const int b    = blockIdx.z;
    const float* img; int C, H, c;
    if (cidx < 64)       { img = p0; C = 64;  H = 112; c = cidx; }
    else if (cidx < 192) { img = p1; C = 128; H = 56;  c = cidx - 64; }
    else                 { img = p2; C = 256; H = 28;  c = cidx - 192; }
    const float gx = gridv[((size_t)b * 2 + 0) * NPTS + n];
    const float gy = gridv[((size_t)b * 2 + 1) * NPTS + n];
    float wx, wy; int x0, x1, y0, y1;
    {
        #pragma clang fp contract(off)
        float ix  = ((gx + 1.0f) * (float)H - 1.0f) * 0.5f;
        float iy  = ((gy + 1.0f) * (float)H - 1.0f) * 0.5f;
        float ix0 = floorf(ix), iy0 = floorf(iy);
        wx = ix - ix0; wy = iy - iy0;
        x0 = min(max((int)ix0, 0),     H - 1);
        x1 = min(max((int)ix0 + 1, 0), H - 1);
        y0 = min(max((int)iy0, 0),     H - 1);
        y1 = min(max((int)iy0 + 1, 0), H - 1);
    }
    const float* pl = img + ((size_t)b * C + c) * H * H;
    float v = pl[y0*H + x0] * (1.f-wx)*(1.f-wy) + pl[y0*H + x1] * wx*(1.f-wy)
            + pl[y1*H + x0] * (1.f-wx)*wy       + pl[y1*H + x1] * wx*wy;
    pooledbf[(size_t)cidx * BN + b * NPTS + n] = __float2bfloat16(v);
}

// ---------------------------------------------------------------------------
// feat = relu(u + v[j0]+v[j1]+v[j2]) -> bf16 into next concat buffer rows 3+
// uv: f32 [512][BN], u = rows 0-255, v = rows 256-511
// ---------------------------------------------------------------------------
__global__ __launch_bounds__(TPB)
void gatherfuse_bf_k(const float* __restrict__ uv, const int* __restrict__ idxp,
                     __hip_bfloat16* __restrict__ Xc)
{
    const int n = blockIdx.x * TPB + threadIdx.x;
    const int c = blockIdx.y;
    const int b = blockIdx.z;
    const int j0 = idxp[0 * BN + b * NPTS + n] & (NPTS - 1);
    const int j1 = idxp[1 * BN + b * NPTS + n] & (NPTS - 1);
    const int j2 = idxp[2 * BN + b * NPTS + n] & (NPTS - 1);
    const float* u = uv + (size_t)c * BN + b * NPTS;
    const float* v = uv + (size_t)(256 + c) * BN + b * NPTS;
    float r = u[n] + v[j0] + v[j1] + v[j2];
    Xc[(size_t)(3 + c) * BN + b * NPTS + n] = __float2bfloat16(fmaxf(r, 0.f));
}

// ---------------------------------------------------------------------------
// layer-3 gather + Wloc head. uv: u3 = rows 0-127, v3 = rows 128-255 (f32).
// ---------------------------------------------------------------------------
__global__ __launch_bounds__(TPB)
void finalfuse_k(const float* __restrict__ uv, const int* __restrict__ idxp,
                 const float* __restrict__ loc,
                 const float* __restrict__ Wloc, const float* __restrict__ bloc,
                 float* __restrict__ outloc, float* __restrict__ outfeat)
{
    __shared__ float wl[393];
    for (int idx = threadIdx.x; idx < 393; idx += TPB) wl[idx] = Wloc[idx];
    __syncthreads();
    const int n = blockIdx.x * TPB + threadIdx.x;
    const int b = blockIdx.y;
    const int j0 = idxp[0 * BN + b * NPTS + n] & (NPTS - 1);
    const int j1 = idxp[1 * BN + b * NPTS + n] & (NPTS - 1);
    const int j2 = idxp[2 * BN + b * NPTS + n] & (NPTS - 1);
    float a0 = bloc[0], a1 = bloc[1], a2 = bloc[2];
    float l[3];
    #pragma unroll
    for (int c = 0; c < 3; ++c) {
        float v = loc[((size_t)b * 3 + c) * NPTS + n];
        l[c] = v;
        a0 += wl[c] * v; a1 += wl[131 + c] * v; a2 += wl[262 + c] * v;
    }
    #pragma unroll 4
    for (int c = 0; c < 128; ++c) {
        const float* u = uv + (size_t)c * BN + b * NPTS;
        const float* v = uv + (size_t)(128 + c) * BN + b * NPTS;
        float f = fmaxf(u[n] + v[j0] + v[j1] + v[j2], 0.f);
        outfeat[((size_t)b * 128 + c) * NPTS + n] = f;
        a0 += wl[3 + c] * f; a1 += wl[134 + c] * f; a2 += wl[265 + c] * f;
    }
    outloc[((size_t)b * 3 + 0) * NPTS + n] = l[0] + tanhf(a0);
    outloc[((size_t)b * 3 + 1) * NPTS + n] = l[1] + tanhf(a1);
    outloc[((size_t)b * 3 + 2) * NPTS + n] = l[2] + tanhf(a2);
}

// ---------------------------------------------------------------------------
__global__ __launch_bounds__(TPB)
void castrows_k(const float* __restrict__ src, __hip_bfloat16* __restrict__ dst,
                int C, int rowOff)
{
    const int n = blockIdx.x * TPB + threadIdx.x;
    const int c = blockIdx.y, b = blockIdx.z;
    dst[(size_t)(rowOff + c) * BN + b * NPTS + n] =
        __float2bfloat16(src[((size_t)b * C + c) * NPTS + n]);
}

__global__ __launch_bounds__(TPB)
void zerobf_k(__hip_bfloat16* __restrict__ dst, int count16B)
{
    int i = blockIdx.x * TPB + threadIdx.x;
    if (i < count16B) ((int4*)dst)[i] = make_int4(0, 0, 0, 0);
}

__global__ __launch_bounds__(TPB)
void wassemble_k(const float* __restrict__ S1, int ld1, int c1,
                 const float* __restrict__ S2, int ld2, int c2,
                 int Kp, __hip_bfloat16* __restrict__ dst)
{
    const int c = blockIdx.x * TPB + threadIdx.x;
    const int r = blockIdx.y;
    if (c >= Kp) return;
    float v = 0.f;
    if (c < c1) v = S1[(size_t)r * ld1 + c];
    else if (c < c1 + c2) v = S2[(size_t)r * ld2 + (c - c1)];
    dst[(size_t)r * Kp + c] = __float2bfloat16(v);
}

__global__ __launch_bounds__(TPB)
void biasfill_k(const float* __restrict__ b2, const float* __restrict__ b3,
                float* __restrict__ bias3, float* __restrict__ bias4)
{
    int i = blockIdx.x * TPB + threadIdx.x;
    if (i < 512) bias3[i] = (i < 256) ? b2[i] : 0.f;
    else if (i < 768) { int j = i - 512; bias4[j] = (j < 128) ? b3[j] : 0.f; }
}

__global__ __launch_bounds__(TPB)
void sentinel_k(float* __restrict__ out, int ntot, float c)
{
    int i = blockIdx.x * TPB + threadIdx.x;
    if (i < ntot) out[i] = c;
}

// ---------------------------------------------------------------------------
extern "C" void kernel_launch(void* const* d_in, const int* in_sizes, int n_in,
                              void* d_out, int out_size, void* d_ws, size_t ws_size,
                              hipStream_t stream)
{
    static const int EXP_INS[26] = {
        49152, 2097152, 3211264, 1605632, 802816,
        8384, 64, 4096, 64, 134, 2,
        114688, 256, 65536, 256,
        99072, 99072, 256, 66304, 66304, 256,
        33152, 33152, 128, 393, 3 };
    constexpr size_t WS_REQ = 16237824ull * 4ull;   // 64.95 MB (proven OK)

    float code = -1.f;
    if (n_in != 26) code = 64.f;
    else {
        bool ok = true;
        for (int i = 0; i < 26; ++i) ok = ok && (in_sizes[i] == EXP_INS[i]);
        if (!ok) code = 24.f;
    }
    if (code < 0.f && out_size != 2146304) code = 32.f;
    if (code < 0.f && ws_size < WS_REQ)    code = 16.f;
    if (code >= 0.f) {
        sentinel_k<<<dim3((out_size + TPB - 1) / TPB), dim3(TPB), 0, stream>>>(
            (float*)d_out, out_size, code);
        return;
    }

    const float* x_loc  = (const float*)d_in[0];
    const float* x_feat = (const float*)d_in[1];
    const float* p0     = (const float*)d_in[2];
    const float* p1     = (const float*)d_in[3];
    const float* p2     = (const float*)d_in[4];
    const float* Ws1 = (const float*)d_in[5];  const float* bs1 = (const float*)d_in[6];
    const float* Ws2 = (const float*)d_in[7];  const float* bs2 = (const float*)d_in[8];
    const float* Wg  = (const float*)d_in[9];  const float* bg  = (const float*)d_in[10];
    const float* Wl1 = (const float*)d_in[11]; const float* bl1 = (const float*)d_in[12];
    const float* Wl2 = (const float*)d_in[13]; const float* bl2 = (const float*)d_in[14];
    const float* Wr1 = (const float*)d_in[15]; const float* Wn1 = (const float*)d_in[16];
    const float* b1  = (const float*)d_in[17];
    const float* Wr2 = (const float*)d_in[18]; const float* Wn2 = (const float*)d_in[19];
    const float* b2  = (const float*)d_in[20];
    const float* Wr3 = (const float*)d_in[21]; const float* Wn3 = (const float*)d_in[22];
    const float* b3  = (const float*)d_in[23];
    const float* Wloc= (const float*)d_in[24]; const float* bloc= (const float*)d_in[25];

    float* ws = (float*)d_ws;
    // region U: uv f32 [512][BN]; hosts h1/h2 early
    float* U  = ws;                       // 8,388,608 f
    float* h1 = U;
    float* h2 = U + 1048576;
    // region P (bf16): pooledbf [448][BN] -> later Xc2 [320][BN]
    __hip_bfloat16* pooledbf = (__hip_bfloat16*)(ws + 8388608);   // 3,670,016 f
    __hip_bfloat16* Xc2      = pooledbf;
    // region X1 (bf16): Xc1 [448][BN] -> later Xc3 [320][BN]
    __hip_bfloat16* Xc1 = (__hip_bfloat16*)(ws + 12058624);       // 3,670,016 f
    __hip_bfloat16* Xc3 = Xc1;
    // small region
    float* S     = ws + 15728640;
    float* gridv = S;                       // 32,768
    int*   idxp  = (int*)(S + 32768);       // 49,152
    float* Wc1u  = S + 81920;               // 65,536
    float* Wc1v  = S + 147456;              // 65,536
    float* bu1   = S + 212992;              // 256
    float* bv1   = S + 213248;              // 256 (contiguous with bu1)
    float* bias3 = S + 213504;              // 512
    float* bias4 = S + 214016;              // 256
    __hip_bfloat16* Wb1 = (__hip_bfloat16*)(S + 214272);  // 256x448
    __hip_bfloat16* Wb2 = (__hip_bfloat16*)(S + 271616);  // 512x448
    __hip_bfloat16* Wb3 = (__hip_bfloat16*)(S + 386304);  // 512x320
    __hip_bfloat16* Wb4 = (__hip_bfloat16*)(S + 468224);  // 256x320
    // total = 16,237,824 floats

    float* out_loc  = (float*)d_out;
    float* out_feat = out_loc + (size_t)BATCH * 3 * NPTS;

    dim3 blk(TPB);
    const int GX = NPTS / TPB;   // 16
    Seg z{nullptr, nullptr, 0, 0};
    const int ZPAD16 = 61 * BN / 8;   // 16B chunks in 61 zero rows

    // weight prep
    wcomp_k<<<dim3(256, 2), blk, 0, stream>>>(Wr1, Wn1, Wl2, bl2, b1,
                                              Wc1u, Wc1v, bu1, bv1);
    biasfill_k<<<dim3(3), blk, 0, stream>>>(b2, b3, bias3, bias4);
    wassemble_k<<<dim3(2, 256), blk, 0, stream>>>(Wl1, 448, 448, nullptr, 0, 0, 448, Wb1);
    wassemble_k<<<dim3(2, 256), blk, 0, stream>>>(Wr1, 387, 131, Wc1u, 256, 256, 448, Wb2);
    wassemble_k<<<dim3(2, 256), blk, 0, stream>>>(Wn1, 387, 131, Wc1v, 256, 256, 448, Wb2 + 256*448);
    wassemble_k<<<dim3(2, 256), blk, 0, stream>>>(Wr2, 259, 259, nullptr, 0, 0, 320, Wb3);
    wassemble_k<<<dim3(2, 256), blk, 0, stream>>>(Wn2, 259, 259, nullptr, 0, 0, 320, Wb3 + 256*320);
    wassemble_k<<<dim3(2, 128), blk, 0, stream>>>(Wr3, 259, 259, nullptr, 0, 0, 320, Wb4);
    wassemble_k<<<dim3(2, 128), blk, 0, stream>>>(Wn3, 259, 259, nullptr, 0, 0, 320, Wb4 + 128*320);

    // front-end (f32)
    conv1x1_k<true><<<dim3(GX, 4, BATCH), blk, 0, stream>>>(
        Seg{x_loc, Ws1, 3, 131}, Seg{x_feat, Ws1 + 3, 128, 131}, 2, 131, bs1, h1, 64);
    conv1x1_k<true><<<dim3(GX, 4, BATCH), blk, 0, stream>>>(
        Seg{h1, Ws2, 64, 64}, z, 1, 64, bs2, h2, 64);
    gridconv_k<<<dim3(GX, BATCH), blk, 0, stream>>>(x_loc, h2, Wg, bg, gridv);
    knn_k<<<dim3(NPTS / 16, BATCH), blk, 0, stream>>>(x_loc, idxp);
    gridsample_bf_k<<<dim3(NPTS / 64, 112, BATCH), blk, 0, stream>>>(
        gridv, p0, p1, p2, pooledbf);

    // Xc1 = [loc; x_feat; t; 0-pad]
    castrows_k<<<dim3(GX, 3, BATCH), blk, 0, stream>>>(x_loc, Xc1, 3, 0);
    castrows_k<<<dim3(GX, 128, BATCH), blk, 0, stream>>>(x_feat, Xc1, 128, 3);
    zerobf_k<<<dim3((ZPAD16 + TPB - 1) / TPB), blk, 0, stream>>>(Xc1 + (size_t)387 * BN, ZPAD16);
    // G1: t = relu(Wl1@pooled + bl1) -> Xc1 rows 131+
    gemm_k<1><<<dim3(128, 2), blk, 0, stream>>>(Wb1, pooledbf, bl1, nullptr, Xc1, 448, 131);

    // Xc2 setup (region reuse: after G1 consumed pooledbf)
    castrows_k<<<dim3(GX, 3, BATCH), blk, 0, stream>>>(x_loc, Xc2, 3, 0);
    zerobf_k<<<dim3((ZPAD16 + TPB - 1) / TPB), blk, 0, stream>>>(Xc2 + (size_t)259 * BN, ZPAD16);
    // G2: [u1; v1] = Wb2 @ Xc1 + [bu1; bv1]
    gemm_k<0><<<dim3(128, 4), blk, 0, stream>>>(Wb2, Xc1, bu1, U, nullptr, 448, 0);
    gatherfuse_bf_k<<<dim3(GX, 256, BATCH), blk, 0, stream>>>(U, idxp, Xc2);

    // Xc3 setup (region reuse: after G2 consumed Xc1)
    castrows_k<<<dim3(GX, 3, BATCH), blk, 0, stream>>>(x_loc, Xc3, 3, 0);
    zerobf_k<<<dim3((ZPAD16 + TPB - 1) / TPB), blk, 0, stream>>>(Xc3 + (size_t)259 * BN, ZPAD16);
    // G3: [u2; v2] = Wb3 @ Xc2 + [b2; 0]
    gemm_k<0><<<dim3(128, 4), blk, 0, stream>>>(Wb3, Xc2, bias3, U, nullptr, 320, 0);
    gatherfuse_bf_k<<<dim3(GX, 256, BATCH), blk, 0, stream>>>(U, idxp, Xc3);

    // G4: [u3; v3] = Wb4 @ Xc3 + [b3; 0]
    gemm_k<0><<<dim3(128, 2), blk, 0, stream>>>(Wb4, Xc3, bias4, U, nullptr, 320, 0);
    finalfuse_k<<<dim3(GX, BATCH), blk, 0, stream>>>(
        U, idxp, x_loc, Wloc, bloc, out_loc, out_feat);
}

// Round 12
// 359.426 us; speedup vs baseline: 1.1756x; 1.1722x over previous
//
#include <hip/hip_runtime.h>
#include <hip/hip_bf16.h>

#define TPB 256
static constexpr int BATCH = 4;
static constexpr int NPTS  = 4096;
static constexpr int BN    = BATCH * NPTS;   // 16384 columns for all GEMMs

typedef __attribute__((ext_vector_type(8))) short short8v;
typedef __attribute__((ext_vector_type(4))) short short4v;
typedef __attribute__((ext_vector_type(4))) float f32x4;

struct Seg { const float* in; const float* W; int C; int ws; };

__device__ __forceinline__ void gload16(const void* g, void* l) {
    __builtin_amdgcn_global_load_lds(
        (const __attribute__((address_space(1))) void*)g,
        (__attribute__((address_space(3))) void*)l, 16, 0, 0);
}

// ---------------------------------------------------------------------------
// MFMA GEMM: D[m][col] = bias[m] + sum_k A[m][k]*B[k][col]
//   A: bf16 [M][Kp] row-major (Kp % 64 == 0), B: bf16 [Kp][BN] row-major.
// Block 256 thr = 4 waves; tile 128x128, BK=64; wave quadrant 64x64 (4x4 frags).
// A-tile: global_load_lds, source-address XOR swizzle, LDS [row][64k] 128B rows.
// B-tile: reg-staged (2x global dwordx4: 8 cols x k-pair) -> ds_write_b32 into
//   k-contiguous LDS [col][64k] with 136B row stride (conflict-free reads).
// Both fragments use slot->k map mu(g4,e)=g4*4+(e&3)+16*(e>>2) (same map on A
// and B => result independent of the HW k-permutation; mu bijective on [0,32)).
// No inline asm: __syncthreads() drains vmcnt (global_load_lds) + lgkmcnt.
// EPI 0: f32 out (+bias). EPI 1: bf16 out (+bias+relu) at row offset rowOff.
// ---------------------------------------------------------------------------
template<int EPI>
__global__ __launch_bounds__(256)
void gemm_k(const __hip_bfloat16* __restrict__ A, const __hip_bfloat16* __restrict__ B,
            const float* __restrict__ bias, float* __restrict__ outF,
            __hip_bfloat16* __restrict__ outB, int Kp, int rowOff)
{
    __shared__ short Alds[8192];   // 128 rows x 64 k (16 KB), 128B rows
    __shared__ short Blds[8704];   // 128 cols x 68 shorts (136B rows, 17 KB)
    const int tid = threadIdx.x, lane = tid & 63, wid = tid >> 6;
    const int wm = wid & 1, wn = wid >> 1;
    const int n0 = blockIdx.x * 128, m0 = blockIdx.y * 128;

    // ---- A staging setup: 1024 granules of 16B, 4 per thread (gload16) ----
    const char* asrc[4]; short* adst[4];
    #pragma unroll
    for (int t = 0; t < 4; ++t) {
        const int g = (wid * 4 + t) * 64 + lane;
        const int arow = g >> 3, ai = g & 7;
        asrc[t] = (const char*)A +
                  (((size_t)(m0 + arow)) * Kp + ((ai ^ (arow & 7)) << 3)) * 2;
        adst[t] = &Alds[(wid * 4 + t) * 512];   // wave-uniform base; HW adds lane*16
    }
    // ---- B staging setup: item q = it*256+tid -> kp = q>>4 (k-pair), c8 = q&15
    const char* bsrc[2]; int bkp[2], bc0[2];
    #pragma unroll
    for (int it = 0; it < 2; ++it) {
        const int q = it * 256 + tid;
        bkp[it] = q >> 4;          // k-pair index 0..31 (k = 2*kp, 2*kp+1)
        bc0[it] = (q & 15) * 8;    // first of 8 columns
        bsrc[it] = (const char*)B +
                   (((size_t)(bkp[it] * 2)) * BN + (n0 + bc0[it])) * 2;
    }

    f32x4 acc[4][4];
    #pragma unroll
    for (int i = 0; i < 4; ++i)
        #pragma unroll
        for (int j = 0; j < 4; ++j) acc[i][j] = (f32x4){0.f, 0.f, 0.f, 0.f};

    const int rl = lane & 15, g4 = lane >> 4;

    const int nkt = Kp >> 6;
    for (int kt = 0; kt < nkt; ++kt) {
        __syncthreads();   // previous iteration's LDS reads complete

        // B: load 8 cols x (k, k+1) into regs (coalesced 16B loads)
        short8v blo[2], bhi[2];
        #pragma unroll
        for (int it = 0; it < 2; ++it) {
            blo[it] = *(const short8v*)(bsrc[it]);
            bhi[it] = *(const short8v*)(bsrc[it] + (size_t)BN * 2);
            bsrc[it] += (size_t)64 * BN * 2;   // advance 64 k-rows
        }
        // A: async global->LDS
        #pragma unroll
        for (int t = 0; t < 4; ++t) {
            gload16(asrc[t], adst[t]);
            asrc[t] += 128;                    // +64 k
        }
        // B: transpose into LDS [col][k] via ds_write_b32 (k-pairs)
        #pragma unroll
        for (int it = 0; it < 2; ++it) {
            #pragma unroll
            for (int j = 0; j < 8; ++j) {
                const int c = bc0[it] + j;
                const int val = ((int)(unsigned short)blo[it][j]) |
                                (((int)(unsigned short)bhi[it][j]) << 16);
                *(int*)((char*)Blds + c * 136 + bkp[it] * 4) = val;
            }
        }
        __syncthreads();   // drains vmcnt(gload_lds) + lgkmcnt(ds_write) + barrier

        #pragma unroll
        for (int ks = 0; ks < 2; ++ks) {
            // A fragments (XOR-swizzled rows)
            short8v af[4];
            #pragma unroll
            for (int mf = 0; mf < 4; ++mf) {
                const int row = wm * 64 + mf * 16 + rl;
                const int base = row * 128, sw = (row & 7) << 4;
                const short4v lo = *(const short4v*)((const char*)Alds +
                                    (base + ((ks * 64 + (g4 << 3)) ^ sw)));
                const short4v hi = *(const short4v*)((const char*)Alds +
                                    (base + ((ks * 64 + (g4 << 3) + 32) ^ sw)));
                af[mf] = __builtin_shufflevector(lo, hi, 0,1,2,3,4,5,6,7);
            }
            // B fragments (linear 136B-stride rows; conflict-free)
            short8v bfv[4];
            #pragma unroll
            for (int nf = 0; nf < 4; ++nf) {
                const int colr = wn * 64 + nf * 16 + rl;
                const char* bp = (const char*)Blds + colr * 136 + ks * 64 + (g4 << 3);
                const short4v lo = *(const short4v*)bp;
                const short4v hi = *(const short4v*)(bp + 32);
                bfv[nf] = __builtin_shufflevector(lo, hi, 0,1,2,3,4,5,6,7);
            }
            #pragma unroll
            for (int mf = 0; mf < 4; ++mf)
                #pragma unroll
                for (int nf = 0; nf < 4; ++nf)
                    acc[mf][nf] = __builtin_amdgcn_mfma_f32_16x16x32_bf16(
                        af[mf], bfv[nf], acc[mf][nf], 0, 0, 0);
        }
    }

    #pragma unroll
    for (int mf = 0; mf < 4; ++mf) {
        #pragma unroll
        for (int i = 0; i < 4; ++i) {
            const int row = m0 + wm * 64 + mf * 16 + g4 * 4 + i;
            const float bs = bias[row];
            #pragma unroll
            for (int nf = 0; nf < 4; ++nf) {
                const int col = n0 + wn * 64 + nf * 16 + rl;
                float v = acc[mf][nf][i] + bs;
                if (EPI == 1) {
                    v = fmaxf(v, 0.f);
                    outB[(size_t)(rowOff + row) * BN + col] = __float2bfloat16(v);
                } else {
                    outF[(size_t)row * BN + col] = v;
                }
            }
        }
    }
}

// ---------------------------------------------------------------------------
// small f32 conv (kept for h1/h2 only)
// ---------------------------------------------------------------------------
template<bool RELU>
__global__ __launch_bounds__(TPB)
void conv1x1_k(Seg s0, Seg s1, int nseg, int Ctot,
               const float* __restrict__ bias, float* __restrict__ out, int O)
{
    __shared__ float Wl[131][16];
    const int n  = blockIdx.x * TPB + threadIdx.x;
    const int o0 = blockIdx.y * 16;
    const int b  = blockIdx.z;
    Seg segs[2] = {s0, s1};
    int off[3]; off[0] = 0;
    #pragma unroll
    for (int k = 0; k < 2; ++k) off[k + 1] = off[k] + (k < nseg ? segs[k].C : 0);
    for (int idx = threadIdx.x; idx < Ctot * 16; idx += TPB) {
        int c = idx >> 4, t = idx & 15;
        int k = (nseg > 1 && c >= off[1]) ? 1 : 0;
        Wl[c][t] = segs[k].W[(size_t)(o0 + t) * segs[k].ws + (c - off[k])];
    }
    __syncthreads();
    float acc[16];
    #pragma unroll
    for (int t = 0; t < 16; ++t) acc[t] = 0.f;
    int cbase = 0;
    for (int k = 0; k < nseg; ++k) {
        const float* ip = segs[k].in + (size_t)b * segs[k].C * NPTS + n;
        const int C = segs[k].C;
        #pragma unroll 4
        for (int cc = 0; cc < C; ++cc) {
            float v = ip[(size_t)cc * NPTS];
            const float4* wr = (const float4*)(&Wl[cbase + cc][0]);
            #pragma unroll
            for (int q = 0; q < 4; ++q) {
                float4 w = wr[q];
                acc[4*q+0] += w.x * v; acc[4*q+1] += w.y * v;
                acc[4*q+2] += w.z * v; acc[4*q+3] += w.w * v;
            }
        }
        cbase += C;
    }
    #pragma unroll
    for (int t = 0; t < 16; ++t) {
        float r = acc[t] + bias[o0 + t];
        if (RELU) r = fmaxf(r, 0.f);
        out[((size_t)b * O + o0 + t) * NPTS + n] = r;
    }
}

// ---------------------------------------------------------------------------
__global__ __launch_bounds__(TPB)
void wcomp_k(const float* __restrict__ Wr1, const float* __restrict__ Wn1,
             const float* __restrict__ Wl2, const float* __restrict__ bl2,
             const float* __restrict__ b1,
             float* __restrict__ Wcu, float* __restrict__ Wcv,
             float* __restrict__ bu, float* __restrict__ bv)
{
    __shared__ float wrow[256];
    const int r = blockIdx.x, isv = blockIdx.y;
    const float* W = isv ? Wn1 : Wr1;
    const int k = threadIdx.x;
    wrow[k] = W[(size_t)r * 387 + 131 + k];
    __syncthreads();
    float acc = 0.f;
    for (int o = 0; o < 256; ++o) acc += wrow[o] * Wl2[(size_t)o * 256 + k];
    (isv ? Wcv : Wcu)[(size_t)r * 256 + k] = acc;
    if (k == 0) {
        float s = 0.f;
        for (int o = 0; o < 256; ++o) s += wrow[o] * bl2[o];
        if (isv) bv[r] = s; else bu[r] = b1[r] + s;
    }
}

// ---------------------------------------------------------------------------
// KNN (K=3). Chunked LDS staging: 1024 points/chunk as float4(x,y,z,sq),
// 16 KB LDS -> all 1024 blocks resident in one dispatch wave (no tail).
// Block = 16 queries x 16 scanners. Serial scan uses STRICT < only: within a
// lane candidates arrive in increasing j, and jax.lax.top_k ties keep the
// lower index = the incumbent, so strict < is exact (verified case-by-case).
// Cross-lane butterfly merge keeps the full lexicographic (d, idx) compare.
// Self-match handled by d := (j==i) ? 3e38 : d (reference adds 1e10 diag).
// ---------------------------------------------------------------------------
__global__ __launch_bounds__(TPB)
void knn_k(const float* __restrict__ loc, int* __restrict__ idxp)
{
    __shared__ float4 pt[1024];   // 16 KB
    const int b = blockIdx.y;
    const float* L = loc + (size_t)b * 3 * NPTS;

    const int ql = threadIdx.x >> 4;     // 16 queries per block
    const int s  = threadIdx.x & 15;     // 16 scanners per query
    const int i  = blockIdx.x * 16 + ql;

    const float xi = L[i], yi = L[NPTS + i], zi = L[2 * NPTS + i];
    float sqi;
    {
        #pragma clang fp contract(off)
        sqi = xi * xi + yi * yi + zi * zi;
    }

    float d0 = 3e38f, d1 = 3e38f, d2 = 3e38f;
    int   i0 = 0x7fffffff, i1 = 0x7fffffff, i2 = 0x7fffffff;

    for (int c = 0; c < NPTS / 1024; ++c) {
        __syncthreads();   // previous chunk's reads complete
        {   // stage 4 points per thread: float4 global loads + sq precompute
            const int base = c * 1024 + threadIdx.x * 4;
            const float4 xs = *(const float4*)(L + base);
            const float4 ys = *(const float4*)(L + NPTS + base);
            const float4 zs = *(const float4*)(L + 2 * NPTS + base);
            float sq0, sq1, sq2, sq3;
            {
                #pragma clang fp contract(off)
                sq0 = xs.x * xs.x + ys.x * ys.x + zs.x * zs.x;
                sq1 = xs.y * xs.y + ys.y * ys.y + zs.y * zs.y;
                sq2 = xs.z * xs.z + ys.z * ys.z + zs.z * zs.z;
                sq3 = xs.w * xs.w + ys.w * ys.w + zs.w * zs.w;
            }
            pt[threadIdx.x * 4 + 0] = make_float4(xs.x, ys.x, zs.x, sq0);
            pt[threadIdx.x * 4 + 1] = make_float4(xs.y, ys.y, zs.y, sq1);
            pt[threadIdx.x * 4 + 2] = make_float4(xs.z, ys.z, zs.z, sq2);
            pt[threadIdx.x * 4 + 3] = make_float4(xs.w, ys.w, zs.w, sq3);
        }
        __syncthreads();

        #pragma unroll 4
        for (int k = 0; k < 1024 / 16; ++k) {
            const int jj = (k << 4) | s;
            const float4 p = pt[jj];
            const int j = (c << 10) | jj;
            float d;
            {
                #pragma clang fp contract(off)
                float dot = xi * p.x + yi * p.y + zi * p.z;
                d = (sqi + p.w) - 2.0f * dot;
            }
            d = (j == i) ? 3e38f : d;
            const bool lt2 = d < d2, lt1 = d < d1, lt0 = d < d0;
            d2 = lt1 ? d1 : (lt2 ? d : d2);  i2 = lt1 ? i1 : (lt2 ? j : i2);
            d1 = lt0 ? d0 : (lt1 ? d : d1);  i1 = lt0 ? i0 : (lt1 ? j : i1);
            d0 = lt0 ? d  : d0;              i0 = lt0 ? j  : i0;
        }
    }

    // butterfly merge across the 16 scanners (full lexicographic tie-break)
    #pragma unroll
    for (int m = 1; m <= 8; m <<= 1) {
        float e0 = __shfl_xor(d0, m), e1 = __shfl_xor(d1, m), e2 = __shfl_xor(d2, m);
        int   j0 = __shfl_xor(i0, m), j1 = __shfl_xor(i1, m), j2 = __shfl_xor(i2, m);
        float ee[3] = {e0, e1, e2};
        int   jj[3] = {j0, j1, j2};
        #pragma unroll
        for (int t = 0; t < 3; ++t) {
            const float e = ee[t]; const int je = jj[t];
            const bool lt2 = (e < d2 || (e == d2 && je < i2));
            const bool lt1 = (e < d1 || (e == d1 && je < i1));
            const bool lt0 = (e < d0 || (e == d0 && je < i0));
            d2 = lt1 ? d1 : (lt2 ? e : d2);  i2 = lt1 ? i1 : (lt2 ? je : i2);
            d1 = lt0 ? d0 : (lt1 ? e : d1);  i1 = lt0 ? i0 : (lt1 ? je : i1);
            d0 = lt0 ? e  : d0;              i0 = lt0 ? je : i0;
        }
    }

    if (s == 0) {
        idxp[0 * BN + b * NPTS + i] = i0;
        idxp[1 * BN + b * NPTS + i] = i1;
        idxp[2 * BN + b * NPTS + i] = i2;
    }
}

// ---------------------------------------------------------------------------
__global__ __launch_bounds__(TPB)
void gridconv_k(const float* __restrict__ loc, const float* __restrict__ h2,
                const float* __restrict__ Wg, const float* __restrict__ bg,
                float* __restrict__ gridv)
{
    const int n = blockIdx.x * TPB + threadIdx.x;
    const int b = blockIdx.y;
    float a0 = bg[0], a1 = bg[1];
    #pragma unroll
    for (int c = 0; c < 3; ++c) {
        float v = loc[((size_t)b * 3 + c) * NPTS + n];
        a0 += Wg[c] * v; a1 += Wg[67 + c] * v;
    }
    const float* hp = h2 + (size_t)b * 64 * NPTS + n;
    #pragma unroll 4
    for (int c = 0; c < 64; ++c) {
        float v = hp[(size_t)c * NPTS];
        a0 += Wg[3 + c] * v; a1 += Wg[70 + c] * v;
    }
    gridv[((size_t)b * 2 + 0) * NPTS + n] = a0;
    gridv[((size_t)b * 2 + 1) * NPTS + n] = a1;
}

// ---------------------------------------------------------------------------
// grid_sample -> bf16 pooled [c][b*NPTS+n]  (coalesced bf16 writes)
// ---------------------------------------------------------------------------
__global__ __launch_bounds__(TPB)
void gridsample_bf_k(const float* __restrict__ gridv, const float* __restrict__ p0,
                     const float* __restrict__ p1, const float* __restrict__ p2,
                     __hip_bfloat16* __restrict__ pooledbf)
{
    const int n    = blockIdx.x * 64 + (threadIdx.x & 63);
    const int cidx = blockIdx.y * 4 + (threadIdx.x >> 6);
    const int b    = blockIdx.z;
    const float* img; int C, H, c;
    if (cidx < 64)       { img = p0; C = 64;  H = 112; c = cidx; }
    else if (cidx < 192) { img = p1; C = 128; H = 56;  c = cidx - 64; }
    else                 { img = p2; C = 256; H = 28;  c = cidx - 192; }
    const float gx = gridv[((size_t)b * 2 + 0) * NPTS + n];
    const float gy = gridv[((size_t)b * 2 + 1) * NPTS + n];
    float wx, wy; int x0, x1, y0, y1;
    {
        #pragma clang fp contract(off)
        float ix  = ((gx + 1.0f) * (float)H - 1.0f) * 0.5f;
        float iy  = ((gy + 1.0f) * (float)H - 1.0f) * 0.5f;
        float ix0 = floorf(ix), iy0 = floorf(iy);
        wx = ix - ix0; wy = iy - iy0;
        x0 = min(max((int)ix0, 0),     H - 1);
        x1 = min(max((int)ix0 + 1, 0), H - 1);
        y0 = min(max((int)iy0, 0),     H - 1);
        y1 = min(max((int)iy0 + 1, 0), H - 1);
    }
    const float* pl = img + ((size_t)b * C + c) * H * H;
    float v = pl[y0*H + x0] * (1.f-wx)*(1.f-wy) + pl[y0*H + x1] * wx*(1.f-wy)
            + pl[y1*H + x0] * (1.f-wx)*wy       + pl[y1*H + x1] * wx*wy;
    pooledbf[(size_t)cidx * BN + b * NPTS + n] = __float2bfloat16(v);
}

// ---------------------------------------------------------------------------
// feat = relu(u + v[j0]+v[j1]+v[j2]) -> bf16 into next concat buffer rows 3+
// uv: f32 [512][BN], u = rows 0-255, v = rows 256-511
// ---------------------------------------------------------------------------
__global__ __launch_bounds__(TPB)
void gatherfuse_bf_k(const float* __restrict__ uv, const int* __restrict__ idxp,
                     __hip_bfloat16* __restrict__ Xc)
{
    const int n = blockIdx.x * TPB + threadIdx.x;
    const int c = blockIdx.y;
    const int b = blockIdx.z;
    const int j0 = idxp[0 * BN + b * NPTS + n] & (NPTS - 1);
    const int j1 = idxp[1 * BN + b * NPTS + n] & (NPTS - 1);
    const int j2 = idxp[2 * BN + b * NPTS + n] & (NPTS - 1);
    const float* u = uv + (size_t)c * BN + b * NPTS;
    const float* v = uv + (size_t)(256 + c) * BN + b * NPTS;
    float r = u[n] + v[j0] + v[j1] + v[j2];
    Xc[(size_t)(3 + c) * BN + b * NPTS + n] = __float2bfloat16(fmaxf(r, 0.f));
}

// ---------------------------------------------------------------------------
// layer-3 gather + Wloc head. uv: u3 = rows 0-127, v3 = rows 128-255 (f32).
// ---------------------------------------------------------------------------
__global__ __launch_bounds__(TPB)
void finalfuse_k(const float* __restrict__ uv, const int* __restrict__ idxp,
                 const float* __restrict__ loc,
                 const float* __restrict__ Wloc, const float* __restrict__ bloc,
                 float* __restrict__ outloc, float* __restrict__ outfeat)
{
    __shared__ float wl[393];
    for (int idx = threadIdx.x; idx < 393; idx += TPB) wl[idx] = Wloc[idx];
    __syncthreads();
    const int n = blockIdx.x * TPB + threadIdx.x;
    const int b = blockIdx.y;
    const int j0 = idxp[0 * BN + b * NPTS + n] & (NPTS - 1);
    const int j1 = idxp[1 * BN + b * NPTS + n] & (NPTS - 1);
    const int j2 = idxp[2 * BN + b * NPTS + n] & (NPTS - 1);
    float a0 = bloc[0], a1 = bloc[1], a2 = bloc[2];
    float l[3];
    #pragma unroll
    for (int c = 0; c < 3; ++c) {
        float v = loc[((size_t)b * 3 + c) * NPTS + n];
        l[c] = v;
        a0 += wl[c] * v; a1 += wl[131 + c] * v; a2 += wl[262 + c] * v;
    }
    #pragma unroll 4
    for (int c = 0; c < 128; ++c) {
        const float* u = uv + (size_t)c * BN + b * NPTS;
        const float* v = uv + (size_t)(128 + c) * BN + b * NPTS;
        float f = fmaxf(u[n] + v[j0] + v[j1] + v[j2], 0.f);
        outfeat[((size_t)b * 128 + c) * NPTS + n] = f;
        a0 += wl[3 + c] * f; a1 += wl[134 + c] * f; a2 += wl[265 + c] * f;
    }
    outloc[((size_t)b * 3 + 0) * NPTS + n] = l[0] + tanhf(a0);
    outloc[((size_t)b * 3 + 1) * NPTS + n] = l[1] + tanhf(a1);
    outloc[((size_t)b * 3 + 2) * NPTS + n] = l[2] + tanhf(a2);
}

// ---------------------------------------------------------------------------
__global__ __launch_bounds__(TPB)
void castrows_k(const float* __restrict__ src, __hip_bfloat16* __restrict__ dst,
                int C, int rowOff)
{
    const int n = blockIdx.x * TPB + threadIdx.x;
    const int c = blockIdx.y, b = blockIdx.z;
    dst[(size_t)(rowOff + c) * BN + b * NPTS + n] =
        __float2bfloat16(src[((size_t)b * C + c) * NPTS + n]);
}

__global__ __launch_bounds__(TPB)
void zerobf_k(__hip_bfloat16* __restrict__ dst, int count16B)
{
    int i = blockIdx.x * TPB + threadIdx.x;
    if (i < count16B) ((int4*)dst)[i] = make_int4(0, 0, 0, 0);
}

__global__ __launch_bounds__(TPB)
void wassemble_k(const float* __restrict__ S1, int ld1, int c1,
                 const float* __restrict__ S2, int ld2, int c2,
                 int Kp, __hip_bfloat16* __restrict__ dst)
{
    const int c = blockIdx.x * TPB + threadIdx.x;
    const int r = blockIdx.y;
    if (c >= Kp) return;
    float v = 0.f;
    if (c < c1) v = S1[(size_t)r * ld1 + c];
    else if (c < c1 + c2) v = S2[(size_t)r * ld2 + (c - c1)];
    dst[(size_t)r * Kp + c] = __float2bfloat16(v);
}

__global__ __launch_bounds__(TPB)
void biasfill_k(const float* __restrict__ b2, const float* __restrict__ b3,
                float* __restrict__ bias3, float* __restrict__ bias4)
{
    int i = blockIdx.x * TPB + threadIdx.x;
    if (i < 512) bias3[i] = (i < 256) ? b2[i] : 0.f;
    else if (i < 768) { int j = i - 512; bias4[j] = (j < 128) ? b3[j] : 0.f; }
}

__global__ __launch_bounds__(TPB)
void sentinel_k(float* __restrict__ out, int ntot, float c)
{
    int i = blockIdx.x * TPB + threadIdx.x;
    if (i < ntot) out[i] = c;
}

// ---------------------------------------------------------------------------
extern "C" void kernel_launch(void* const* d_in, const int* in_sizes, int n_in,
                              void* d_out, int out_size, void* d_ws, size_t ws_size,
                              hipStream_t stream)
{
    static const int EXP_INS[26] = {
        49152, 2097152, 3211264, 1605632, 802816,
        8384, 64, 4096, 64, 134, 2,
        114688, 256, 65536, 256,
        99072, 99072, 256, 66304, 66304, 256,
        33152, 33152, 128, 393, 3 };
    constexpr size_t WS_REQ = 16237824ull * 4ull;   // 64.95 MB (proven OK)

    float code = -1.f;
    if (n_in != 26) code = 64.f;
    else {
        bool ok = true;
        for (int i = 0; i < 26; ++i) ok = ok && (in_sizes[i] == EXP_INS[i]);
        if (!ok) code = 24.f;
    }
    if (code < 0.f && out_size != 2146304) code = 32.f;
    if (code < 0.f && ws_size < WS_REQ)    code = 16.f;
    if (code >= 0.f) {
        sentinel_k<<<dim3((out_size + TPB - 1) / TPB), dim3(TPB), 0, stream>>>(
            (float*)d_out, out_size, code);
        return;
    }

    const float* x_loc  = (const float*)d_in[0];
    const float* x_feat = (const float*)d_in[1];
    const float* p0     = (const float*)d_in[2];
    const float* p1     = (const float*)d_in[3];
    const float* p2     = (const float*)d_in[4];
    const float* Ws1 = (const float*)d_in[5];  const float* bs1 = (const float*)d_in[6];
    const float* Ws2 = (const float*)d_in[7];  const float* bs2 = (const float*)d_in[8];
    const float* Wg  = (const float*)d_in[9];  const float* bg  = (const float*)d_in[10];
    const float* Wl1 = (const float*)d_in[11]; const float* bl1 = (const float*)d_in[12];
    const float* Wl2 = (const float*)d_in[13]; const float* bl2 = (const float*)d_in[14];
    const float* Wr1 = (const float*)d_in[15]; const float* Wn1 = (const float*)d_in[16];
    const float* b1  = (const float*)d_in[17];
    const float* Wr2 = (const float*)d_in[18]; const float* Wn2 = (const float*)d_in[19];
    const float* b2  = (const float*)d_in[20];
    const float* Wr3 = (const float*)d_in[21]; const float* Wn3 = (const float*)d_in[22];
    const float* b3  = (const float*)d_in[23];
    const float* Wloc= (const float*)d_in[24]; const float* bloc= (const float*)d_in[25];

    float* ws = (float*)d_ws;
    // region U: uv f32 [512][BN]; hosts h1/h2 early
    float* U  = ws;                       // 8,388,608 f
    float* h1 = U;
    float* h2 = U + 1048576;
    // region P (bf16): pooledbf [448][BN] -> later Xc2 [320][BN]
    __hip_bfloat16* pooledbf = (__hip_bfloat16*)(ws + 8388608);   // 3,670,016 f
    __hip_bfloat16* Xc2      = pooledbf;
    // region X1 (bf16): Xc1 [448][BN] -> later Xc3 [320][BN]
    __hip_bfloat16* Xc1 = (__hip_bfloat16*)(ws + 12058624);       // 3,670,016 f
    __hip_bfloat16* Xc3 = Xc1;
    // small region
    float* S     = ws + 15728640;
    float* gridv = S;                       // 32,768
    int*   idxp  = (int*)(S + 32768);       // 49,152
    float* Wc1u  = S + 81920;               // 65,536
    float* Wc1v  = S + 147456;              // 65,536
    float* bu1   = S + 212992;              // 256
    float* bv1   = S + 213248;              // 256 (contiguous with bu1)
    float* bias3 = S + 213504;              // 512
    float* bias4 = S + 214016;              // 256
    __hip_bfloat16* Wb1 = (__hip_bfloat16*)(S + 214272);  // 256x448
    __hip_bfloat16* Wb2 = (__hip_bfloat16*)(S + 271616);  // 512x448
    __hip_bfloat16* Wb3 = (__hip_bfloat16*)(S + 386304);  // 512x320
    __hip_bfloat16* Wb4 = (__hip_bfloat16*)(S + 468224);  // 256x320
    // total = 16,237,824 floats

    float* out_loc  = (float*)d_out;
    float* out_feat = out_loc + (size_t)BATCH * 3 * NPTS;

    dim3 blk(TPB);
    const int GX = NPTS / TPB;   // 16
    Seg z{nullptr, nullptr, 0, 0};
    const int ZPAD16 = 61 * BN / 8;   // 16B chunks in 61 zero rows

    // weight prep
    wcomp_k<<<dim3(256, 2), blk, 0, stream>>>(Wr1, Wn1, Wl2, bl2, b1,
                                              Wc1u, Wc1v, bu1, bv1);
    biasfill_k<<<dim3(3), blk, 0, stream>>>(b2, b3, bias3, bias4);
    wassemble_k<<<dim3(2, 256), blk, 0, stream>>>(Wl1, 448, 448, nullptr, 0, 0, 448, Wb1);
    wassemble_k<<<dim3(2, 256), blk, 0, stream>>>(Wr1, 387, 131, Wc1u, 256, 256, 448, Wb2);
    wassemble_k<<<dim3(2, 256), blk, 0, stream>>>(Wn1, 387, 131, Wc1v, 256, 256, 448, Wb2 + 256*448);
    wassemble_k<<<dim3(2, 256), blk, 0, stream>>>(Wr2, 259, 259, nullptr, 0, 0, 320, Wb3);
    wassemble_k<<<dim3(2, 256), blk, 0, stream>>>(Wn2, 259, 259, nullptr, 0, 0, 320, Wb3 + 256*320);
    wassemble_k<<<dim3(2, 128), blk, 0, stream>>>(Wr3, 259, 259, nullptr, 0, 0, 320, Wb4);
    wassemble_k<<<dim3(2, 128), blk, 0, stream>>>(Wn3, 259, 259, nullptr, 0, 0, 320, Wb4 + 128*320);

    // front-end (f32)
    conv1x1_k<true><<<dim3(GX, 4, BATCH), blk, 0, stream>>>(
        Seg{x_loc, Ws1, 3, 131}, Seg{x_feat, Ws1 + 3, 128, 131}, 2, 131, bs1, h1, 64);
    conv1x1_k<true><<<dim3(GX, 4, BATCH), blk, 0, stream>>>(
        Seg{h1, Ws2, 64, 64}, z, 1, 64, bs2, h2, 64);
    gridconv_k<<<dim3(GX, BATCH), blk, 0, stream>>>(x_loc, h2, Wg, bg, gridv);
    knn_k<<<dim3(NPTS / 16, BATCH), blk, 0, stream>>>(x_loc, idxp);
    gridsample_bf_k<<<dim3(NPTS / 64, 112, BATCH), blk, 0, stream>>>(
        gridv, p0, p1, p2, pooledbf);

    // Xc1 = [loc; x_feat; t; 0-pad]
    castrows_k<<<dim3(GX, 3, BATCH), blk, 0, stream>>>(x_loc, Xc1, 3, 0);
    castrows_k<<<dim3(GX, 128, BATCH), blk, 0, stream>>>(x_feat, Xc1, 128, 3);
    zerobf_k<<<dim3((ZPAD16 + TPB - 1) / TPB), blk, 0, stream>>>(Xc1 + (size_t)387 * BN, ZPAD16);
    // G1: t = relu(Wl1@pooled + bl1) -> Xc1 rows 131+
    gemm_k<1><<<dim3(128, 2), blk, 0, stream>>>(Wb1, pooledbf, bl1, nullptr, Xc1, 448, 131);

    // Xc2 setup (region reuse: after G1 consumed pooledbf)
    castrows_k<<<dim3(GX, 3, BATCH), blk, 0, stream>>>(x_loc, Xc2, 3, 0);
    zerobf_k<<<dim3((ZPAD16 + TPB - 1) / TPB), blk, 0, stream>>>(Xc2 + (size_t)259 * BN, ZPAD16);
    // G2: [u1; v1] = Wb2 @ Xc1 + [bu1; bv1]
    gemm_k<0><<<dim3(128, 4), blk, 0, stream>>>(Wb2, Xc1, bu1, U, nullptr, 448, 0);
    gatherfuse_bf_k<<<dim3(GX, 256, BATCH), blk, 0, stream>>>(U, idxp, Xc2);

    // Xc3 setup (region reuse: after G2 consumed Xc1)
    castrows_k<<<dim3(GX, 3, BATCH), blk, 0, stream>>>(x_loc, Xc3, 3, 0);
    zerobf_k<<<dim3((ZPAD16 + TPB - 1) / TPB), blk, 0, stream>>>(Xc3 + (size_t)259 * BN, ZPAD16);
    // G3: [u2; v2] = Wb3 @ Xc2 + [b2; 0]
    gemm_k<0><<<dim3(128, 4), blk, 0, stream>>>(Wb3, Xc2, bias3, U, nullptr, 320, 0);
    gatherfuse_bf_k<<<dim3(GX, 256, BATCH), blk, 0, stream>>>(U, idxp, Xc3);

    // G4: [u3; v3] = Wb4 @ Xc3 + [b3; 0]
    gemm_k<0><<<dim3(128, 2), blk, 0, stream>>>(Wb4, Xc3, bias4, U, nullptr, 320, 0);
    finalfuse_k<<<dim3(GX, BATCH), blk, 0, stream>>>(
        U, idxp, x_loc, Wloc, bloc, out_loc, out_feat);
}

// Round 14
// 327.286 us; speedup vs baseline: 1.2910x; 1.0982x over previous
//
#include <hip/hip_runtime.h>
#include <hip/hip_bf16.h>

#define TPB 256
static constexpr int BATCH = 4;
static constexpr int NPTS  = 4096;
static constexpr int BN    = BATCH * NPTS;   // 16384 columns for all GEMMs

typedef __attribute__((ext_vector_type(8))) short short8v;
typedef __attribute__((ext_vector_type(4))) short short4v;
typedef __attribute__((ext_vector_type(4))) float f32x4;

struct Seg { const float* in; const float* W; int C; int ws; };

__device__ __forceinline__ void gload16(const void* g, void* l) {
    __builtin_amdgcn_global_load_lds(
        (const __attribute__((address_space(1))) void*)g,
        (__attribute__((address_space(3))) void*)l, 16, 0, 0);
}

// ---------------------------------------------------------------------------
// MFMA GEMM: D[m][col] = bias[m] + sum_k A[m][k]*B[k][col]
//   A: bf16 [M][Kp] row-major (Kp % 64 == 0), B: bf16 [Kp][BN] row-major.
// Block 256 thr = 4 waves; tile 128x128, BK=64; wave quadrant 64x64 (4x4 frags).
// A-tile: global_load_lds, source-address XOR swizzle, LDS [row][64k] 128B rows.
// B-tile: reg-staged -> ds_write_b32 into k-contiguous LDS [col][64k], 136B
// row stride (conflict-free). Same slot->k map on A and B => HW-perm-proof.
// EPI 0: f32 out (+bias). EPI 1: bf16 out (+bias+relu) at row offset rowOff.
// ---------------------------------------------------------------------------
template<int EPI>
__global__ __launch_bounds__(256)
void gemm_k(const __hip_bfloat16* __restrict__ A, const __hip_bfloat16* __restrict__ B,
            const float* __restrict__ bias, float* __restrict__ outF,
            __hip_bfloat16* __restrict__ outB, int Kp, int rowOff)
{
    __shared__ short Alds[8192];
    __shared__ short Blds[8704];
    const int tid = threadIdx.x, lane = tid & 63, wid = tid >> 6;
    const int wm = wid & 1, wn = wid >> 1;
    const int n0 = blockIdx.x * 128, m0 = blockIdx.y * 128;

    const char* asrc[4]; short* adst[4];
    #pragma unroll
    for (int t = 0; t < 4; ++t) {
        const int g = (wid * 4 + t) * 64 + lane;
        const int arow = g >> 3, ai = g & 7;
        asrc[t] = (const char*)A +
                  (((size_t)(m0 + arow)) * Kp + ((ai ^ (arow & 7)) << 3)) * 2;
        adst[t] = &Alds[(wid * 4 + t) * 512];
    }
    const char* bsrc[2]; int bkp[2], bc0[2];
    #pragma unroll
    for (int it = 0; it < 2; ++it) {
        const int q = it * 256 + tid;
        bkp[it] = q >> 4;
        bc0[it] = (q & 15) * 8;
        bsrc[it] = (const char*)B +
                   (((size_t)(bkp[it] * 2)) * BN + (n0 + bc0[it])) * 2;
    }

    f32x4 acc[4][4];
    #pragma unroll
    for (int i = 0; i < 4; ++i)
        #pragma unroll
        for (int j = 0; j < 4; ++j) acc[i][j] = (f32x4){0.f, 0.f, 0.f, 0.f};

    const int rl = lane & 15, g4 = lane >> 4;

    const int nkt = Kp >> 6;
    for (int kt = 0; kt < nkt; ++kt) {
        __syncthreads();
        short8v blo[2], bhi[2];
        #pragma unroll
        for (int it = 0; it < 2; ++it) {
            blo[it] = *(const short8v*)(bsrc[it]);
            bhi[it] = *(const short8v*)(bsrc[it] + (size_t)BN * 2);
            bsrc[it] += (size_t)64 * BN * 2;
        }
        #pragma unroll
        for (int t = 0; t < 4; ++t) {
            gload16(asrc[t], adst[t]);
            asrc[t] += 128;
        }
        #pragma unroll
        for (int it = 0; it < 2; ++it) {
            #pragma unroll
            for (int j = 0; j < 8; ++j) {
                const int c = bc0[it] + j;
                const int val = ((int)(unsigned short)blo[it][j]) |
                                (((int)(unsigned short)bhi[it][j]) << 16);
                *(int*)((char*)Blds + c * 136 + bkp[it] * 4) = val;
            }
        }
        __syncthreads();

        #pragma unroll
        for (int ks = 0; ks < 2; ++ks) {
            short8v af[4];
            #pragma unroll
            for (int mf = 0; mf < 4; ++mf) {
                const int row = wm * 64 + mf * 16 + rl;
                const int base = row * 128, sw = (row & 7) << 4;
                const short4v lo = *(const short4v*)((const char*)Alds +
                                    (base + ((ks * 64 + (g4 << 3)) ^ sw)));
                const short4v hi = *(const short4v*)((const char*)Alds +
                                    (base + ((ks * 64 + (g4 << 3) + 32) ^ sw)));
                af[mf] = __builtin_shufflevector(lo, hi, 0,1,2,3,4,5,6,7);
            }
            short8v bfv[4];
            #pragma unroll
            for (int nf = 0; nf < 4; ++nf) {
                const int colr = wn * 64 + nf * 16 + rl;
                const char* bp = (const char*)Blds + colr * 136 + ks * 64 + (g4 << 3);
                const short4v lo = *(const short4v*)bp;
                const short4v hi = *(const short4v*)(bp + 32);
                bfv[nf] = __builtin_shufflevector(lo, hi, 0,1,2,3,4,5,6,7);
            }
            #pragma unroll
            for (int mf = 0; mf < 4; ++mf)
                #pragma unroll
                for (int nf = 0; nf < 4; ++nf)
                    acc[mf][nf] = __builtin_amdgcn_mfma_f32_16x16x32_bf16(
                        af[mf], bfv[nf], acc[mf][nf], 0, 0, 0);
        }
    }

    #pragma unroll
    for (int mf = 0; mf < 4; ++mf) {
        #pragma unroll
        for (int i = 0; i < 4; ++i) {
            const int row = m0 + wm * 64 + mf * 16 + g4 * 4 + i;
            const float bs = bias[row];
            #pragma unroll
            for (int nf = 0; nf < 4; ++nf) {
                const int col = n0 + wn * 64 + nf * 16 + rl;
                float v = acc[mf][nf][i] + bs;
                if (EPI == 1) {
                    v = fmaxf(v, 0.f);
                    outB[(size_t)(rowOff + row) * BN + col] = __float2bfloat16(v);
                } else {
                    outF[(size_t)row * BN + col] = v;
                }
            }
        }
    }
}

// ---------------------------------------------------------------------------
// small f32 conv — h1/h2 only. The grid path MUST stay f32: bf16 there
// amplifies via bilinear sampling (dix/dgx = H/2) into a >1.0 output error
// (measured in R13). FLOP cost is trivial (~7 us) — do not MFMA-ize.
// ---------------------------------------------------------------------------
template<bool RELU>
__global__ __launch_bounds__(TPB)
void conv1x1_k(Seg s0, Seg s1, int nseg, int Ctot,
               const float* __restrict__ bias, float* __restrict__ out, int O)
{
    __shared__ float Wl[131][16];
    const int n  = blockIdx.x * TPB + threadIdx.x;
    const int o0 = blockIdx.y * 16;
    const int b  = blockIdx.z;
    Seg segs[2] = {s0, s1};
    int off[3]; off[0] = 0;
    #pragma unroll
    for (int k = 0; k < 2; ++k) off[k + 1] = off[k] + (k < nseg ? segs[k].C : 0);
    for (int idx = threadIdx.x; idx < Ctot * 16; idx += TPB) {
        int c = idx >> 4, t = idx & 15;
        int k = (nseg > 1 && c >= off[1]) ? 1 : 0;
        Wl[c][t] = segs[k].W[(size_t)(o0 + t) * segs[k].ws + (c - off[k])];
    }
    __syncthreads();
    float acc[16];
    #pragma unroll
    for (int t = 0; t < 16; ++t) acc[t] = 0.f;
    int cbase = 0;
    for (int k = 0; k < nseg; ++k) {
        const float* ip = segs[k].in + (size_t)b * segs[k].C * NPTS + n;
        const int C = segs[k].C;
        #pragma unroll 4
        for (int cc = 0; cc < C; ++cc) {
            float v = ip[(size_t)cc * NPTS];
            const float4* wr = (const float4*)(&Wl[cbase + cc][0]);
            #pragma unroll
            for (int q = 0; q < 4; ++q) {
                float4 w = wr[q];
                acc[4*q+0] += w.x * v; acc[4*q+1] += w.y * v;
                acc[4*q+2] += w.z * v; acc[4*q+3] += w.w * v;
            }
        }
        cbase += C;
    }
    #pragma unroll
    for (int t = 0; t < 16; ++t) {
        float r = acc[t] + bias[o0 + t];
        if (RELU) r = fmaxf(r, 0.f);
        out[((size_t)b * O + o0 + t) * NPTS + n] = r;
    }
}

// ---------------------------------------------------------------------------
__global__ __launch_bounds__(TPB)
void wcomp_k(const float* __restrict__ Wr1, const float* __restrict__ Wn1,
             const float* __restrict__ Wl2, const float* __restrict__ bl2,
             const float* __restrict__ b1,
             float* __restrict__ Wcu, float* __restrict__ Wcv,
             float* __restrict__ bu, float* __restrict__ bv)
{
    __shared__ float wrow[256];
    const int r = blockIdx.x, isv = blockIdx.y;
    const float* W = isv ? Wn1 : Wr1;
    const int k = threadIdx.x;
    wrow[k] = W[(size_t)r * 387 + 131 + k];
    __syncthreads();
    float acc = 0.f;
    for (int o = 0; o < 256; ++o) acc += wrow[o] * Wl2[(size_t)o * 256 + k];
    (isv ? Wcv : Wcu)[(size_t)r * 256 + k] = acc;
    if (k == 0) {
        float s = 0.f;
        for (int o = 0; o < 256; ++o) s += wrow[o] * bl2[o];
        if (isv) bv[r] = s; else bu[r] = b1[r] + s;
    }
}

// ---------------------------------------------------------------------------
// KNN (K=3). Chunked float4(x,y,z,sq) staging (16 KB LDS); 16q x 16s blocks.
// Strict < in serial scan (exact: in-lane candidates arrive in increasing j;
// top_k ties keep lower index = incumbent). Butterfly keeps full lex compare.
// ---------------------------------------------------------------------------
__global__ __launch_bounds__(TPB)
void knn_k(const float* __restrict__ loc, int* __restrict__ idxp)
{
    __shared__ float4 pt[1024];
    const int b = blockIdx.y;
    const float* L = loc + (size_t)b * 3 * NPTS;

    const int ql = threadIdx.x >> 4;
    const int s  = threadIdx.x & 15;
    const int i  = blockIdx.x * 16 + ql;

    const float xi = L[i], yi = L[NPTS + i], zi = L[2 * NPTS + i];
    float sqi;
    {
        #pragma clang fp contract(off)
        sqi = xi * xi + yi * yi + zi * zi;
    }

    float d0 = 3e38f, d1 = 3e38f, d2 = 3e38f;
    int   i0 = 0x7fffffff, i1 = 0x7fffffff, i2 = 0x7fffffff;

    for (int c = 0; c < NPTS / 1024; ++c) {
        __syncthreads();
        {
            const int base = c * 1024 + threadIdx.x * 4;
            const float4 xs = *(const float4*)(L + base);
            const float4 ys = *(const float4*)(L + NPTS + base);
            const float4 zs = *(const float4*)(L + 2 * NPTS + base);
            float sq0, sq1, sq2, sq3;
            {
                #pragma clang fp contract(off)
                sq0 = xs.x * xs.x + ys.x * ys.x + zs.x * zs.x;
                sq1 = xs.y * xs.y + ys.y * ys.y + zs.y * zs.y;
                sq2 = xs.z * xs.z + ys.z * ys.z + zs.z * zs.z;
                sq3 = xs.w * xs.w + ys.w * ys.w + zs.w * zs.w;
            }
            pt[threadIdx.x * 4 + 0] = make_float4(xs.x, ys.x, zs.x, sq0);
            pt[threadIdx.x * 4 + 1] = make_float4(xs.y, ys.y, zs.y, sq1);
            pt[threadIdx.x * 4 + 2] = make_float4(xs.z, ys.z, zs.z, sq2);
            pt[threadIdx.x * 4 + 3] = make_float4(xs.w, ys.w, zs.w, sq3);
        }
        __syncthreads();

        #pragma unroll 4
        for (int k = 0; k < 1024 / 16; ++k) {
            const int jj = (k << 4) | s;
            const float4 p = pt[jj];
            const int j = (c << 10) | jj;
            float d;
            {
                #pragma clang fp contract(off)
                float dot = xi * p.x + yi * p.y + zi * p.z;
                d = (sqi + p.w) - 2.0f * dot;
            }
            d = (j == i) ? 3e38f : d;
            const bool lt2 = d < d2, lt1 = d < d1, lt0 = d < d0;
            d2 = lt1 ? d1 : (lt2 ? d : d2);  i2 = lt1 ? i1 : (lt2 ? j : i2);
            d1 = lt0 ? d0 : (lt1 ? d : d1);  i1 = lt0 ? i0 : (lt1 ? j : i1);
            d0 = lt0 ? d  : d0;              i0 = lt0 ? j  : i0;
        }
    }

    #pragma unroll
    for (int m = 1; m <= 8; m <<= 1) {
        float e0 = __shfl_xor(d0, m), e1 = __shfl_xor(d1, m), e2 = __shfl_xor(d2, m);
        int   j0 = __shfl_xor(i0, m), j1 = __shfl_xor(i1, m), j2 = __shfl_xor(i2, m);
        float ee[3] = {e0, e1, e2};
        int   jj[3] = {j0, j1, j2};
        #pragma unroll
        for (int t = 0; t < 3; ++t) {
            const float e = ee[t]; const int je = jj[t];
            const bool lt2 = (e < d2 || (e == d2 && je < i2));
            const bool lt1 = (e < d1 || (e == d1 && je < i1));
            const bool lt0 = (e < d0 || (e == d0 && je < i0));
            d2 = lt1 ? d1 : (lt2 ? e : d2);  i2 = lt1 ? i1 : (lt2 ? je : i2);
            d1 = lt0 ? d0 : (lt1 ? e : d1);  i1 = lt0 ? i0 : (lt1 ? je : i1);
            d0 = lt0 ? e  : d0;              i0 = lt0 ? je : i0;
        }
    }

    if (s == 0) {
        idxp[0 * BN + b * NPTS + i] = i0;
        idxp[1 * BN + b * NPTS + i] = i1;
        idxp[2 * BN + b * NPTS + i] = i2;
    }
}

// ---------------------------------------------------------------------------
// grid = Wg @ [loc; h2] + bg.  h2 layout: [b][c][NPTS] (f32 conv output).
// ---------------------------------------------------------------------------
__global__ __launch_bounds__(TPB)
void gridconv_k(const float* __restrict__ loc, const float* __restrict__ h2,
                const float* __restrict__ Wg, const float* __restrict__ bg,
                float* __restrict__ gridv)
{
    const int n = blockIdx.x * TPB + threadIdx.x;
    const int b = blockIdx.y;
    float a0 = bg[0], a1 = bg[1];
    #pragma unroll
    for (int c = 0; c < 3; ++c) {
        float v = loc[((size_t)b * 3 + c) * NPTS + n];
        a0 += Wg[c] * v; a1 += Wg[67 + c] * v;
    }
    const float* hp = h2 + (size_t)b * 64 * NPTS + n;
    #pragma unroll 4
    for (int c = 0; c < 64; ++c) {
        float v = hp[(size_t)c * NPTS];
        a0 += Wg[3 + c] * v; a1 += Wg[70 + c] * v;
    }
    gridv[((size_t)b * 2 + 0) * NPTS + n] = a0;
    gridv[((size_t)b * 2 + 1) * NPTS + n] = a1;
}

// ---------------------------------------------------------------------------
__global__ __launch_bounds__(TPB)
void gridsample_bf_k(const float* __restrict__ gridv, const float* __restrict__ p0,
                     const float* __restrict__ p1, const float* __restrict__ p2,
                     __hip_bfloat16* __restrict__ pooledbf)
{
    const int n    = blockIdx.x * 64 + (threadIdx.x & 63);
    const int cidx = blockIdx.y * 4 + (threadIdx.x >> 6);
    const int b    = blockIdx.z;
    const float* img; int C, H, c;
    if (cidx < 64)       { img = p0; C = 64;  H = 112; c = cidx; }
    else if (cidx < 192) { img = p1; C = 128; H = 56;  c = cidx - 64; }
    else                 { img = p2; C = 256; H = 28;  c = cidx - 192; }
    const float gx = gridv[((size_t)b * 2 + 0) * NPTS + n];
    const float gy = gridv[((size_t)b * 2 + 1) * NPTS + n];
    float wx, wy; int x0, x1, y0, y1;
    {
        #pragma clang fp contract(off)
        float ix  = ((gx + 1.0f) * (float)H - 1.0f) * 0.5f;
        float iy  = ((gy + 1.0f) * (float)H - 1.0f) * 0.5f;
        float ix0 = floorf(ix), iy0 = floorf(iy);
        wx = ix - ix0; wy = iy - iy0;
        x0 = min(max((int)ix0, 0),     H - 1);
        x1 = min(max((int)ix0 + 1, 0), H - 1);
        y0 = min(max((int)iy0, 0),     H - 1);
        y1 = min(max((int)iy0 + 1, 0), H - 1);
    }
    const float* pl = img + ((size_t)b * C + c) * H * H;
    float v = pl[y0*H + x0] * (1.f-wx)*(1.f-wy) + pl[y0*H + x1] * wx*(1.f-wy)
            + pl[y1*H + x0] * (1.f-wx)*wy       + pl[y1*H + x1] * wx*wy;
    pooledbf[(size_t)cidx * BN + b * NPTS + n] = __float2bfloat16(v);
}

// ---------------------------------------------------------------------------
// feat = relu(u + v[j0]+v[j1]+v[j2]) -> bf16 into next concat buffer rows 3+
// ---------------------------------------------------------------------------
__global__ __launch_bounds__(TPB)
void gatherfuse_bf_k(const float* __restrict__ uv, const int* __restrict__ idxp,
                     __hip_bfloat16* __restrict__ Xc)
{
    const int n = blockIdx.x * TPB + threadIdx.x;
    const int c = blockIdx.y;
    const int b = blockIdx.z;
    const int j0 = idxp[0 * BN + b * NPTS + n] & (NPTS - 1);
    const int j1 = idxp[1 * BN + b * NPTS + n] & (NPTS - 1);
    const int j2 = idxp[2 * BN + b * NPTS + n] & (NPTS - 1);
    const float* u = uv + (size_t)c * BN + b * NPTS;
    const float* v = uv + (size_t)(256 + c) * BN + b * NPTS;
    float r = u[n] + v[j0] + v[j1] + v[j2];
    Xc[(size_t)(3 + c) * BN + b * NPTS + n] = __float2bfloat16(fmaxf(r, 0.f));
}

// ---------------------------------------------------------------------------
// layer-3 gather + Wloc head, channel-parallel: 16 points x 16 channel-groups
// per block; grid (NPTS/16, BATCH) = 1024 blocks. Per-thread 8 channels, then
// LDS reduce [16cg][16pt][3]; cg==0 lanes finish loc terms + tanh.
// ---------------------------------------------------------------------------
__global__ __launch_bounds__(TPB)
void finalfuse_k(const float* __restrict__ uv, const int* __restrict__ idxp,
                 const float* __restrict__ loc,
                 const float* __restrict__ Wloc, const float* __restrict__ bloc,
                 float* __restrict__ outloc, float* __restrict__ outfeat)
{
    __shared__ float wl[393];
    __shared__ float part[16][16][3];
    for (int idx = threadIdx.x; idx < 393; idx += TPB) wl[idx] = Wloc[idx];
    __syncthreads();

    const int nl = threadIdx.x & 15, cg = threadIdx.x >> 4;
    const int n = blockIdx.x * 16 + nl;
    const int b = blockIdx.y;
    const int j0 = idxp[0 * BN + b * NPTS + n] & (NPTS - 1);
    const int j1 = idxp[1 * BN + b * NPTS + n] & (NPTS - 1);
    const int j2 = idxp[2 * BN + b * NPTS + n] & (NPTS - 1);

    float a0 = 0.f, a1 = 0.f, a2 = 0.f;
    #pragma unroll
    for (int cc = 0; cc < 8; ++cc) {
        const int c = cg * 8 + cc;
        const float* u = uv + (size_t)c * BN + b * NPTS;
        const float* v = uv + (size_t)(128 + c) * BN + b * NPTS;
        float f = fmaxf(u[n] + v[j0] + v[j1] + v[j2], 0.f);
        outfeat[((size_t)b * 128 + c) * NPTS + n] = f;
        a0 += wl[3 + c] * f; a1 += wl[134 + c] * f; a2 += wl[265 + c] * f;
    }
    part[cg][nl][0] = a0; part[cg][nl][1] = a1; part[cg][nl][2] = a2;
    __syncthreads();

    if (cg == 0) {
        float b0 = bloc[0], b1v = bloc[1], b2v = bloc[2];
        float l[3];
        #pragma unroll
        for (int c = 0; c < 3; ++c) {
            float v = loc[((size_t)b * 3 + c) * NPTS + n];
            l[c] = v;
            b0 += wl[c] * v; b1v += wl[131 + c] * v; b2v += wl[262 + c] * v;
        }
        #pragma unroll
        for (int g = 0; g < 16; ++g) {
            b0 += part[g][nl][0]; b1v += part[g][nl][1]; b2v += part[g][nl][2];
        }
        outloc[((size_t)b * 3 + 0) * NPTS + n] = l[0] + tanhf(b0);
        outloc[((size_t)b * 3 + 1) * NPTS + n] = l[1] + tanhf(b1v);
        outloc[((size_t)b * 3 + 2) * NPTS + n] = l[2] + tanhf(b2v);
    }
}

// ---------------------------------------------------------------------------
__global__ __launch_bounds__(TPB)
void castrows_k(const float* __restrict__ src, __hip_bfloat16* __restrict__ dst,
                int C, int rowOff)
{
    const int n = blockIdx.x * TPB + threadIdx.x;
    const int c = blockIdx.y, b = blockIdx.z;
    dst[(size_t)(rowOff + c) * BN + b * NPTS + n] =
        __float2bfloat16(src[((size_t)b * C + c) * NPTS + n]);
}

__global__ __launch_bounds__(TPB)
void zerobf_k(__hip_bfloat16* __restrict__ dst, int count16B)
{
    int i = blockIdx.x * TPB + threadIdx.x;
    if (i < count16B) ((int4*)dst)[i] = make_int4(0, 0, 0, 0);
}

// rows1: valid source rows (rows >= rows1 zero-filled)
__global__ __launch_bounds__(TPB)
void wassemble_k(const float* __restrict__ S1, int ld1, int c1, int rows1,
                 const float* __restrict__ S2, int ld2, int c2,
                 int Kp, __hip_bfloat16* __restrict__ dst)
{
    const int c = blockIdx.x * TPB + threadIdx.x;
    const int r = blockIdx.y;
    if (c >= Kp) return;
    float v = 0.f;
    if (r < rows1) {
        if (c < c1) v = S1[(size_t)r * ld1 + c];
        else if (c < c1 + c2) v = S2[(size_t)r * ld2 + (c - c1)];
    }
    dst[(size_t)r * Kp + c] = __float2bfloat16(v);
}

__global__ __launch_bounds__(TPB)
void biasfill_k(const float* __restrict__ b2, const float* __restrict__ b3,
                float* __restrict__ bias3, float* __restrict__ bias4)
{
    int i = blockIdx.x * TPB + threadIdx.x;
    if (i < 512) bias3[i] = (i < 256) ? b2[i] : 0.f;
    else if (i < 768) { int j = i - 512; bias4[j] = (j < 128) ? b3[j] : 0.f; }
}

__global__ __launch_bounds__(TPB)
void sentinel_k(float* __restrict__ out, int ntot, float c)
{
    int i = blockIdx.x * TPB + threadIdx.x;
    if (i < ntot) out[i] = c;
}

// ---------------------------------------------------------------------------
extern "C" void kernel_launch(void* const* d_in, const int* in_sizes, int n_in,
                              void* d_out, int out_size, void* d_ws, size_t ws_size,
                              hipStream_t stream)
{
    static const int EXP_INS[26] = {
        49152, 2097152, 3211264, 1605632, 802816,
        8384, 64, 4096, 64, 134, 2,
        114688, 256, 65536, 256,
        99072, 99072, 256, 66304, 66304, 256,
        33152, 33152, 128, 393, 3 };
    constexpr size_t WS_REQ = 16237824ull * 4ull;

    float code = -1.f;
    if (n_in != 26) code = 64.f;
    else {
        bool ok = true;
        for (int i = 0; i < 26; ++i) ok = ok && (in_sizes[i] == EXP_INS[i]);
        if (!ok) code = 24.f;
    }
    if (code < 0.f && out_size != 2146304) code = 32.f;
    if (code < 0.f && ws_size < WS_REQ)    code = 16.f;
    if (code >= 0.f) {
        sentinel_k<<<dim3((out_size + TPB - 1) / TPB), dim3(TPB), 0, stream>>>(
            (float*)d_out, out_size, code);
        return;
    }

    const float* x_loc  = (const float*)d_in[0];
    const float* x_feat = (const float*)d_in[1];
    const float* p0     = (const float*)d_in[2];
    const float* p1     = (const float*)d_in[3];
    const float* p2     = (const float*)d_in[4];
    const float* Ws1 = (const float*)d_in[5];  const float* bs1 = (const float*)d_in[6];
    const float* Ws2 = (const float*)d_in[7];  const float* bs2 = (const float*)d_in[8];
    const float* Wg  = (const float*)d_in[9];  const float* bg  = (const float*)d_in[10];
    const float* Wl1 = (const float*)d_in[11]; const float* bl1 = (const float*)d_in[12];
    const float* Wl2 = (const float*)d_in[13]; const float* bl2 = (const float*)d_in[14];
    const float* Wr1 = (const float*)d_in[15]; const float* Wn1 = (const float*)d_in[16];
    const float* b1  = (const float*)d_in[17];
    const float* Wr2 = (const float*)d_in[18]; const float* Wn2 = (const float*)d_in[19];
    const float* b2  = (const float*)d_in[20];
    const float* Wr3 = (const float*)d_in[21]; const float* Wn3 = (const float*)d_in[22];
    const float* b3  = (const float*)d_in[23];
    const float* Wloc= (const float*)d_in[24]; const float* bloc= (const float*)d_in[25];

    float* ws = (float*)d_ws;
    // region U: uv f32 [512][BN]; hosts h1/h2 early (f32 conv outputs)
    float* U  = ws;                       // 8,388,608 f
    float* h1 = U;
    float* h2 = U + 1048576;
    // region P (bf16): pooledbf [448][BN] -> later Xc2 [320][BN]
    __hip_bfloat16* pooledbf = (__hip_bfloat16*)(ws + 8388608);
    __hip_bfloat16* Xc2      = pooledbf;
    // region X1 (bf16): Xc1 [448][BN] -> later Xc3 [320][BN]
    __hip_bfloat16* Xc1 = (__hip_bfloat16*)(ws + 12058624);
    __hip_bfloat16* Xc3 = Xc1;
    // small region
    float* S     = ws + 15728640;
    float* gridv = S;                       // 32,768
    int*   idxp  = (int*)(S + 32768);       // 49,152
    float* Wc1u  = S + 81920;               // 65,536
    float* Wc1v  = S + 147456;              // 65,536
    float* bu1   = S + 212992;              // 256
    float* bv1   = S + 213248;              // 256 (contiguous with bu1)
    float* bias3 = S + 213504;              // 512
    float* bias4 = S + 214016;              // 256
    __hip_bfloat16* Wb1 = (__hip_bfloat16*)(S + 214272);  // 256x448
    __hip_bfloat16* Wb2 = (__hip_bfloat16*)(S + 271616);  // 512x448
    __hip_bfloat16* Wb3 = (__hip_bfloat16*)(S + 386304);  // 512x320
    __hip_bfloat16* Wb4 = (__hip_bfloat16*)(S + 468224);  // 256x320
    // total = 16,237,824 floats

    float* out_loc  = (float*)d_out;
    float* out_feat = out_loc + (size_t)BATCH * 3 * NPTS;

    dim3 blk(TPB);
    const int GX = NPTS / TPB;   // 16
    Seg z{nullptr, nullptr, 0, 0};
    const int ZPAD16 = 61 * BN / 8;

    // weight prep
    wcomp_k<<<dim3(256, 2), blk, 0, stream>>>(Wr1, Wn1, Wl2, bl2, b1,
                                              Wc1u, Wc1v, bu1, bv1);
    biasfill_k<<<dim3(3), blk, 0, stream>>>(b2, b3, bias3, bias4);
    wassemble_k<<<dim3(2, 256), blk, 0, stream>>>(Wl1, 448, 448, 256, nullptr, 0, 0, 448, Wb1);
    wassemble_k<<<dim3(2, 256), blk, 0, stream>>>(Wr1, 387, 131, 256, Wc1u, 256, 256, 448, Wb2);
    wassemble_k<<<dim3(2, 256), blk, 0, stream>>>(Wn1, 387, 131, 256, Wc1v, 256, 256, 448, Wb2 + 256*448);
    wassemble_k<<<dim3(2, 256), blk, 0, stream>>>(Wr2, 259, 259, 256, nullptr, 0, 0, 320, Wb3);
    wassemble_k<<<dim3(2, 256), blk, 0, stream>>>(Wn2, 259, 259, 256, nullptr, 0, 0, 320, Wb3 + 256*320);
    wassemble_k<<<dim3(2, 128), blk, 0, stream>>>(Wr3, 259, 259, 128, nullptr, 0, 0, 320, Wb4);
    wassemble_k<<<dim3(2, 128), blk, 0, stream>>>(Wn3, 259, 259, 128, nullptr, 0, 0, 320, Wb4 + 128*320);

    // front-end (f32 — precision-critical grid path)
    conv1x1_k<true><<<dim3(GX, 4, BATCH), blk, 0, stream>>>(
        Seg{x_loc, Ws1, 3, 131}, Seg{x_feat, Ws1 + 3, 128, 131}, 2, 131, bs1, h1, 64);
    conv1x1_k<true><<<dim3(GX, 4, BATCH), blk, 0, stream>>>(
        Seg{h1, Ws2, 64, 64}, z, 1, 64, bs2, h2, 64);
    gridconv_k<<<dim3(GX, BATCH), blk, 0, stream>>>(x_loc, h2, Wg, bg, gridv);
    knn_k<<<dim3(NPTS / 16, BATCH), blk, 0, stream>>>(x_loc, idxp);
    gridsample_bf_k<<<dim3(NPTS / 64, 112, BATCH), blk, 0, stream>>>(
        gridv, p0, p1, p2, pooledbf);

    // Xc1 = [loc; x_feat; t; 0-pad]
    castrows_k<<<dim3(GX, 3, BATCH), blk, 0, stream>>>(x_loc, Xc1, 3, 0);
    castrows_k<<<dim3(GX, 128, BATCH), blk, 0, stream>>>(x_feat, Xc1, 128, 3);
    zerobf_k<<<dim3((ZPAD16 + TPB - 1) / TPB), blk, 0, stream>>>(Xc1 + (size_t)387 * BN, ZPAD16);
    // G1: t = relu(Wl1@pooled + bl1) -> Xc1 rows 131+
    gemm_k<1><<<dim3(128, 2), blk, 0, stream>>>(Wb1, pooledbf, bl1, nullptr, Xc1, 448, 131);

    // Xc2 setup (pooledbf consumed by G1)
    castrows_k<<<dim3(GX, 3, BATCH), blk, 0, stream>>>(x_loc, Xc2, 3, 0);
    zerobf_k<<<dim3((ZPAD16 + TPB - 1) / TPB), blk, 0, stream>>>(Xc2 + (size_t)259 * BN, ZPAD16);
    // G2: [u1; v1] = Wb2 @ Xc1 + [bu1; bv1]
    gemm_k<0><<<dim3(128, 4), blk, 0, stream>>>(Wb2, Xc1, bu1, U, nullptr, 448, 0);
    gatherfuse_bf_k<<<dim3(GX, 256, BATCH), blk, 0, stream>>>(U, idxp, Xc2);

    // Xc3 setup (Xc1 consumed by G2)
    castrows_k<<<dim3(GX, 3, BATCH), blk, 0, stream>>>(x_loc, Xc3, 3, 0);
    zerobf_k<<<dim3((ZPAD16 + TPB - 1) / TPB), blk, 0, stream>>>(Xc3 + (size_t)259 * BN, ZPAD16);
    // G3: [u2; v2] = Wb3 @ Xc2 + [b2; 0]
    gemm_k<0><<<dim3(128, 4), blk, 0, stream>>>(Wb3, Xc2, bias3, U, nullptr, 320, 0);
    gatherfuse_bf_k<<<dim3(GX, 256, BATCH), blk, 0, stream>>>(U, idxp, Xc3);

    // G4: [u3; v3] = Wb4 @ Xc3 + [b3; 0]
    gemm_k<0><<<dim3(128, 2), blk, 0, stream>>>(Wb4, Xc3, bias4, U, nullptr, 320, 0);
    // fused layer-3 gather + Wloc head (channel-parallel, 1024 blocks)
    finalfuse_k<<<dim3(NPTS / 16, BATCH), blk, 0, stream>>>(
        U, idxp, x_loc, Wloc, bloc, out_loc, out_feat);
}

// Round 15
// 306.692 us; speedup vs baseline: 1.3777x; 1.0671x over previous
//
#include <hip/hip_runtime.h>
#include <hip/hip_bf16.h>

#define TPB 256
static constexpr int BATCH = 4;
static constexpr int NPTS  = 4096;
static constexpr int BN    = BATCH * NPTS;   // 16384 columns for all GEMMs

typedef __attribute__((ext_vector_type(8))) short short8v;
typedef __attribute__((ext_vector_type(4))) short short4v;
typedef __attribute__((ext_vector_type(4))) float f32x4;

struct Seg { const float* in; const float* W; int C; int ws; };

__device__ __forceinline__ void gload16(const void* g, void* l) {
    __builtin_amdgcn_global_load_lds(
        (const __attribute__((address_space(1))) void*)g,
        (__attribute__((address_space(3))) void*)l, 16, 0, 0);
}

// ---------------------------------------------------------------------------
// MFMA GEMM: D[m][col] = bias[m] + sum_k A[m][k]*B[k][col]
//   A: bf16 [M][Kp] row-major (Kp % 64 == 0), B: bf16 [Kp][BN] row-major.
// Block 256 thr = 4 waves; tile 128x128, BK=64; wave quadrant 64x64 (4x4 frags).
// A-tile: global_load_lds, source-address XOR swizzle, LDS [row][64k] 128B rows.
// B-tile: reg-staged -> ds_write_b32 into k-contiguous LDS [col][64k], 136B
// row stride (conflict-free). Same slot->k map on A and B => HW-perm-proof.
// EPI 0: f32 out (+bias). EPI 1: bf16 out (+bias+relu) at row offset rowOff.
// ---------------------------------------------------------------------------
template<int EPI>
__global__ __launch_bounds__(256)
void gemm_k(const __hip_bfloat16* __restrict__ A, const __hip_bfloat16* __restrict__ B,
            const float* __restrict__ bias, float* __restrict__ outF,
            __hip_bfloat16* __restrict__ outB, int Kp, int rowOff)
{
    __shared__ short Alds[8192];
    __shared__ short Blds[8704];
    const int tid = threadIdx.x, lane = tid & 63, wid = tid >> 6;
    const int wm = wid & 1, wn = wid >> 1;
    const int n0 = blockIdx.x * 128, m0 = blockIdx.y * 128;

    const char* asrc[4]; short* adst[4];
    #pragma unroll
    for (int t = 0; t < 4; ++t) {
        const int g = (wid * 4 + t) * 64 + lane;
        const int arow = g >> 3, ai = g & 7;
        asrc[t] = (const char*)A +
                  (((size_t)(m0 + arow)) * Kp + ((ai ^ (arow & 7)) << 3)) * 2;
        adst[t] = &Alds[(wid * 4 + t) * 512];
    }
    const char* bsrc[2]; int bkp[2], bc0[2];
    #pragma unroll
    for (int it = 0; it < 2; ++it) {
        const int q = it * 256 + tid;
        bkp[it] = q >> 4;
        bc0[it] = (q & 15) * 8;
        bsrc[it] = (const char*)B +
                   (((size_t)(bkp[it] * 2)) * BN + (n0 + bc0[it])) * 2;
    }

    f32x4 acc[4][4];
    #pragma unroll
    for (int i = 0; i < 4; ++i)
        #pragma unroll
        for (int j = 0; j < 4; ++j) acc[i][j] = (f32x4){0.f, 0.f, 0.f, 0.f};

    const int rl = lane & 15, g4 = lane >> 4;

    const int nkt = Kp >> 6;
    for (int kt = 0; kt < nkt; ++kt) {
        __syncthreads();
        short8v blo[2], bhi[2];
        #pragma unroll
        for (int it = 0; it < 2; ++it) {
            blo[it] = *(const short8v*)(bsrc[it]);
            bhi[it] = *(const short8v*)(bsrc[it] + (size_t)BN * 2);
            bsrc[it] += (size_t)64 * BN * 2;
        }
        #pragma unroll
        for (int t = 0; t < 4; ++t) {
            gload16(asrc[t], adst[t]);
            asrc[t] += 128;
        }
        #pragma unroll
        for (int it = 0; it < 2; ++it) {
            #pragma unroll
            for (int j = 0; j < 8; ++j) {
                const int c = bc0[it] + j;
                const int val = ((int)(unsigned short)blo[it][j]) |
                                (((int)(unsigned short)bhi[it][j]) << 16);
                *(int*)((char*)Blds + c * 136 + bkp[it] * 4) = val;
            }
        }
        __syncthreads();

        #pragma unroll
        for (int ks = 0; ks < 2; ++ks) {
            short8v af[4];
            #pragma unroll
            for (int mf = 0; mf < 4; ++mf) {
                const int row = wm * 64 + mf * 16 + rl;
                const int base = row * 128, sw = (row & 7) << 4;
                const short4v lo = *(const short4v*)((const char*)Alds +
                                    (base + ((ks * 64 + (g4 << 3)) ^ sw)));
                const short4v hi = *(const short4v*)((const char*)Alds +
                                    (base + ((ks * 64 + (g4 << 3) + 32) ^ sw)));
                af[mf] = __builtin_shufflevector(lo, hi, 0,1,2,3,4,5,6,7);
            }
            short8v bfv[4];
            #pragma unroll
            for (int nf = 0; nf < 4; ++nf) {
                const int colr = wn * 64 + nf * 16 + rl;
                const char* bp = (const char*)Blds + colr * 136 + ks * 64 + (g4 << 3);
                const short4v lo = *(const short4v*)bp;
                const short4v hi = *(const short4v*)(bp + 32);
                bfv[nf] = __builtin_shufflevector(lo, hi, 0,1,2,3,4,5,6,7);
            }
            #pragma unroll
            for (int mf = 0; mf < 4; ++mf)
                #pragma unroll
                for (int nf = 0; nf < 4; ++nf)
                    acc[mf][nf] = __builtin_amdgcn_mfma_f32_16x16x32_bf16(
                        af[mf], bfv[nf], acc[mf][nf], 0, 0, 0);
        }
    }

    #pragma unroll
    for (int mf = 0; mf < 4; ++mf) {
        #pragma unroll
        for (int i = 0; i < 4; ++i) {
            const int row = m0 + wm * 64 + mf * 16 + g4 * 4 + i;
            const float bs = bias[row];
            #pragma unroll
            for (int nf = 0; nf < 4; ++nf) {
                const int col = n0 + wn * 64 + nf * 16 + rl;
                float v = acc[mf][nf][i] + bs;
                if (EPI == 1) {
                    v = fmaxf(v, 0.f);
                    outB[(size_t)(rowOff + row) * BN + col] = __float2bfloat16(v);
                } else {
                    outF[(size_t)row * BN + col] = v;
                }
            }
        }
    }
}

// ---------------------------------------------------------------------------
// small f32 conv — h1/h2 only (grid path must stay f32; R13 lesson: bf16
// coordinate error x H/2 through bilinear sampling breaks the output).
// OT = outputs per thread (8 doubles block count vs 16 -> better latency hide).
// ---------------------------------------------------------------------------
template<bool RELU, int OT>
__global__ __launch_bounds__(TPB)
void conv1x1_k(Seg s0, Seg s1, int nseg, int Ctot,
               const float* __restrict__ bias, float* __restrict__ out, int O)
{
    __shared__ float Wl[131][OT];
    const int n  = blockIdx.x * TPB + threadIdx.x;
    const int o0 = blockIdx.y * OT;
    const int b  = blockIdx.z;
    Seg segs[2] = {s0, s1};
    int off[3]; off[0] = 0;
    #pragma unroll
    for (int k = 0; k < 2; ++k) off[k + 1] = off[k] + (k < nseg ? segs[k].C : 0);
    for (int idx = threadIdx.x; idx < Ctot * OT; idx += TPB) {
        int c = idx / OT, t = idx % OT;
        int k = (nseg > 1 && c >= off[1]) ? 1 : 0;
        Wl[c][t] = segs[k].W[(size_t)(o0 + t) * segs[k].ws + (c - off[k])];
    }
    __syncthreads();
    float acc[OT];
    #pragma unroll
    for (int t = 0; t < OT; ++t) acc[t] = 0.f;
    int cbase = 0;
    for (int k = 0; k < nseg; ++k) {
        const float* ip = segs[k].in + (size_t)b * segs[k].C * NPTS + n;
        const int C = segs[k].C;
        #pragma unroll 4
        for (int cc = 0; cc < C; ++cc) {
            float v = ip[(size_t)cc * NPTS];
            const float4* wr = (const float4*)(&Wl[cbase + cc][0]);
            #pragma unroll
            for (int q = 0; q < OT / 4; ++q) {
                float4 w = wr[q];
                acc[4*q+0] += w.x * v; acc[4*q+1] += w.y * v;
                acc[4*q+2] += w.z * v; acc[4*q+3] += w.w * v;
            }
        }
        cbase += C;
    }
    #pragma unroll
    for (int t = 0; t < OT; ++t) {
        float r = acc[t] + bias[o0 + t];
        if (RELU) r = fmaxf(r, 0.f);
        out[((size_t)b * O + o0 + t) * NPTS + n] = r;
    }
}

// ---------------------------------------------------------------------------
__global__ __launch_bounds__(TPB)
void wcomp_k(const float* __restrict__ Wr1, const float* __restrict__ Wn1,
             const float* __restrict__ Wl2, const float* __restrict__ bl2,
             const float* __restrict__ b1,
             float* __restrict__ Wcu, float* __restrict__ Wcv,
             float* __restrict__ bu, float* __restrict__ bv)
{
    __shared__ float wrow[256];
    const int r = blockIdx.x, isv = blockIdx.y;
    const float* W = isv ? Wn1 : Wr1;
    const int k = threadIdx.x;
    wrow[k] = W[(size_t)r * 387 + 131 + k];
    __syncthreads();
    float acc = 0.f;
    for (int o = 0; o < 256; ++o) acc += wrow[o] * Wl2[(size_t)o * 256 + k];
    (isv ? Wcv : Wcu)[(size_t)r * 256 + k] = acc;
    if (k == 0) {
        float s = 0.f;
        for (int o = 0; o < 256; ++o) s += wrow[o] * bl2[o];
        if (isv) bv[r] = s; else bu[r] = b1[r] + s;
    }
}

// ---------------------------------------------------------------------------
// KNN (K=3). Chunked float4(x,y,z,sq) staging; conflict-free writes
// (pt[t*256+tid]: consecutive lanes -> consecutive float4s). 16q x 16s.
// Strict < serial scan (exact; ties keep lower index = incumbent);
// butterfly merge keeps full lexicographic compare.
// ---------------------------------------------------------------------------
__global__ __launch_bounds__(TPB)
void knn_k(const float* __restrict__ loc, int* __restrict__ idxp)
{
    __shared__ float4 pt[1024];
    const int b = blockIdx.y;
    const float* L = loc + (size_t)b * 3 * NPTS;

    const int ql = threadIdx.x >> 4;
    const int s  = threadIdx.x & 15;
    const int i  = blockIdx.x * 16 + ql;

    const float xi = L[i], yi = L[NPTS + i], zi = L[2 * NPTS + i];
    float sqi;
    {
        #pragma clang fp contract(off)
        sqi = xi * xi + yi * yi + zi * zi;
    }

    float d0 = 3e38f, d1 = 3e38f, d2 = 3e38f;
    int   i0 = 0x7fffffff, i1 = 0x7fffffff, i2 = 0x7fffffff;

    for (int c = 0; c < NPTS / 1024; ++c) {
        __syncthreads();
        {
            const int base = c * 1024;
            #pragma unroll
            for (int t = 0; t < 4; ++t) {
                const int p = t * 256 + threadIdx.x;
                const float x = L[base + p];
                const float y = L[NPTS + base + p];
                const float z = L[2 * NPTS + base + p];
                float sq;
                {
                    #pragma clang fp contract(off)
                    sq = x * x + y * y + z * z;
                }
                pt[p] = make_float4(x, y, z, sq);
            }
        }
        __syncthreads();

        #pragma unroll 4
        for (int k = 0; k < 1024 / 16; ++k) {
            const int jj = (k << 4) | s;
            const float4 p = pt[jj];
            const int j = (c << 10) | jj;
            float d;
            {
                #pragma clang fp contract(off)
                float dot = xi * p.x + yi * p.y + zi * p.z;
                d = (sqi + p.w) - 2.0f * dot;
            }
            d = (j == i) ? 3e38f : d;
            const bool lt2 = d < d2, lt1 = d < d1, lt0 = d < d0;
            d2 = lt1 ? d1 : (lt2 ? d : d2);  i2 = lt1 ? i1 : (lt2 ? j : i2);
            d1 = lt0 ? d0 : (lt1 ? d : d1);  i1 = lt0 ? i0 : (lt1 ? j : i1);
            d0 = lt0 ? d  : d0;              i0 = lt0 ? j  : i0;
        }
    }

    #pragma unroll
    for (int m = 1; m <= 8; m <<= 1) {
        float e0 = __shfl_xor(d0, m), e1 = __shfl_xor(d1, m), e2 = __shfl_xor(d2, m);
        int   j0 = __shfl_xor(i0, m), j1 = __shfl_xor(i1, m), j2 = __shfl_xor(i2, m);
        float ee[3] = {e0, e1, e2};
        int   jj[3] = {j0, j1, j2};
        #pragma unroll
        for (int t = 0; t < 3; ++t) {
            const float e = ee[t]; const int je = jj[t];
            const bool lt2 = (e < d2 || (e == d2 && je < i2));
            const bool lt1 = (e < d1 || (e == d1 && je < i1));
            const bool lt0 = (e < d0 || (e == d0 && je < i0));
            d2 = lt1 ? d1 : (lt2 ? e : d2);  i2 = lt1 ? i1 : (lt2 ? je : i2);
            d1 = lt0 ? d0 : (lt1 ? e : d1);  i1 = lt0 ? i0 : (lt1 ? je : i1);
            d0 = lt0 ? e  : d0;              i0 = lt0 ? je : i0;
        }
    }

    if (s == 0) {
        idxp[0 * BN + b * NPTS + i] = i0;
        idxp[1 * BN + b * NPTS + i] = i1;
        idxp[2 * BN + b * NPTS + i] = i2;
    }
}

// ---------------------------------------------------------------------------
// grid = Wg @ [loc; h2] + bg.  h2 layout: [b][c][NPTS] (f32 conv output).
// ---------------------------------------------------------------------------
__global__ __launch_bounds__(TPB)
void gridconv_k(const float* __restrict__ loc, const float* __restrict__ h2,
                const float* __restrict__ Wg, const float* __restrict__ bg,
                float* __restrict__ gridv)
{
    const int n = blockIdx.x * TPB + threadIdx.x;
    const int b = blockIdx.y;
    float a0 = bg[0], a1 = bg[1];
    #pragma unroll
    for (int c = 0; c < 3; ++c) {
        float v = loc[((size_t)b * 3 + c) * NPTS + n];
        a0 += Wg[c] * v; a1 += Wg[67 + c] * v;
    }
    const float* hp = h2 + (size_t)b * 64 * NPTS + n;
    #pragma unroll 4
    for (int c = 0; c < 64; ++c) {
        float v = hp[(size_t)c * NPTS];
        a0 += Wg[3 + c] * v; a1 += Wg[70 + c] * v;
    }
    gridv[((size_t)b * 2 + 0) * NPTS + n] = a0;
    gridv[((size_t)b * 2 + 1) * NPTS + n] = a1;
}

// ---------------------------------------------------------------------------
__global__ __launch_bounds__(TPB)
void gridsample_bf_k(const float* __restrict__ gridv, const float* __restrict__ p0,
                     const float* __restrict__ p1, const float* __restrict__ p2,
                     __hip_bfloat16* __restrict__ pooledbf)
{
    const int n    = blockIdx.x * 64 + (threadIdx.x & 63);
    const int cidx = blockIdx.y * 4 + (threadIdx.x >> 6);
    const int b    = blockIdx.z;
    const float* img; int C, H, c;
    if (cidx < 64)       { img = p0; C = 64;  H = 112; c = cidx; }
    else if (cidx < 192) { img = p1; C = 128; H = 56;  c = cidx - 64; }
    else                 { img = p2; C = 256; H = 28;  c = cidx - 192; }
    const float gx = gridv[((size_t)b * 2 + 0) * NPTS + n];
    const float gy = gridv[((size_t)b * 2 + 1) * NPTS + n];
    float wx, wy; int x0, x1, y0, y1;
    {
        #pragma clang fp contract(off)
        float ix  = ((gx + 1.0f) * (float)H - 1.0f) * 0.5f;
        float iy  = ((gy + 1.0f) * (float)H - 1.0f) * 0.5f;
        float ix0 = floorf(ix), iy0 = floorf(iy);
        wx = ix - ix0; wy = iy - iy0;
        x0 = min(max((int)ix0, 0),     H - 1);
        x1 = min(max((int)ix0 + 1, 0), H - 1);
        y0 = min(max((int)iy0, 0),     H - 1);
        y1 = min(max((int)iy0 + 1, 0), H - 1);
    }
    const float* pl = img + ((size_t)b * C + c) * H * H;
    float v = pl[y0*H + x0] * (1.f-wx)*(1.f-wy) + pl[y0*H + x1] * wx*(1.f-wy)
            + pl[y1*H + x0] * (1.f-wx)*wy       + pl[y1*H + x1] * wx*wy;
    pooledbf[(size_t)cidx * BN + b * NPTS + n] = __float2bfloat16(v);
}

// ---------------------------------------------------------------------------
// feat = relu(u + v[j0]+v[j1]+v[j2]) -> bf16, v-row staged in LDS (16 KB).
// Block per (c, b): coalesced v/u reads; gathers hit LDS not L2.
// ---------------------------------------------------------------------------
__global__ __launch_bounds__(TPB)
void gatherfuse_bf_k(const float* __restrict__ uv, const int* __restrict__ idxp,
                     __hip_bfloat16* __restrict__ Xc)
{
    __shared__ float vl[NPTS];   // 16 KB
    const int c = blockIdx.x;
    const int b = blockIdx.y;
    const float* u = uv + (size_t)c * BN + b * NPTS;
    const float* v = uv + (size_t)(256 + c) * BN + b * NPTS;
    #pragma unroll
    for (int t = 0; t < NPTS / TPB; ++t)
        vl[t * TPB + threadIdx.x] = v[t * TPB + threadIdx.x];
    __syncthreads();

    #pragma unroll
    for (int t = 0; t < NPTS / TPB; ++t) {
        const int n = t * TPB + threadIdx.x;
        const int j0 = idxp[0 * BN + b * NPTS + n] & (NPTS - 1);
        const int j1 = idxp[1 * BN + b * NPTS + n] & (NPTS - 1);
        const int j2 = idxp[2 * BN + b * NPTS + n] & (NPTS - 1);
        float r = u[n] + vl[j0] + vl[j1] + vl[j2];
        Xc[(size_t)(3 + c) * BN + b * NPTS + n] = __float2bfloat16(fmaxf(r, 0.f));
    }
}

// ---------------------------------------------------------------------------
// layer-3 gather + Wloc head, channel-parallel (1024 blocks).
// ---------------------------------------------------------------------------
__global__ __launch_bounds__(TPB)
void finalfuse_k(const float* __restrict__ uv, const int* __restrict__ idxp,
                 const float* __restrict__ loc,
                 const float* __restrict__ Wloc, const float* __restrict__ bloc,
                 float* __restrict__ outloc, float* __restrict__ outfeat)
{
    __shared__ float wl[393];
    __shared__ float part[16][16][3];
    for (int idx = threadIdx.x; idx < 393; idx += TPB) wl[idx] = Wloc[idx];
    __syncthreads();

    const int nl = threadIdx.x & 15, cg = threadIdx.x >> 4;
    const int n = blockIdx.x * 16 + nl;
    const int b = blockIdx.y;
    const int j0 = idxp[0 * BN + b * NPTS + n] & (NPTS - 1);
    const int j1 = idxp[1 * BN + b * NPTS + n] & (NPTS - 1);
    const int j2 = idxp[2 * BN + b * NPTS + n] & (NPTS - 1);

    float a0 = 0.f, a1 = 0.f, a2 = 0.f;
    #pragma unroll
    for (int cc = 0; cc < 8; ++cc) {
        const int c = cg * 8 + cc;
        const float* u = uv + (size_t)c * BN + b * NPTS;
        const float* v = uv + (size_t)(128 + c) * BN + b * NPTS;
        float f = fmaxf(u[n] + v[j0] + v[j1] + v[j2], 0.f);
        outfeat[((size_t)b * 128 + c) * NPTS + n] = f;
        a0 += wl[3 + c] * f; a1 += wl[134 + c] * f; a2 += wl[265 + c] * f;
    }
    part[cg][nl][0] = a0; part[cg][nl][1] = a1; part[cg][nl][2] = a2;
    __syncthreads();

    if (cg == 0) {
        float b0 = bloc[0], b1v = bloc[1], b2v = bloc[2];
        float l[3];
        #pragma unroll
        for (int c = 0; c < 3; ++c) {
            float v = loc[((size_t)b * 3 + c) * NPTS + n];
            l[c] = v;
            b0 += wl[c] * v; b1v += wl[131 + c] * v; b2v += wl[262 + c] * v;
        }
        #pragma unroll
        for (int g = 0; g < 16; ++g) {
            b0 += part[g][nl][0]; b1v += part[g][nl][1]; b2v += part[g][nl][2];
        }
        outloc[((size_t)b * 3 + 0) * NPTS + n] = l[0] + tanhf(b0);
        outloc[((size_t)b * 3 + 1) * NPTS + n] = l[1] + tanhf(b1v);
        outloc[((size_t)b * 3 + 2) * NPTS + n] = l[2] + tanhf(b2v);
    }
}

// ---------------------------------------------------------------------------
__global__ __launch_bounds__(TPB)
void castrows_k(const float* __restrict__ src, __hip_bfloat16* __restrict__ dst,
                int C, int rowOff)
{
    const int n = blockIdx.x * TPB + threadIdx.x;
    const int c = blockIdx.y, b = blockIdx.z;
    dst[(size_t)(rowOff + c) * BN + b * NPTS + n] =
        __float2bfloat16(src[((size_t)b * C + c) * NPTS + n]);
}

__global__ __launch_bounds__(TPB)
void zerobf_k(__hip_bfloat16* __restrict__ dst, int count16B)
{
    int i = blockIdx.x * TPB + threadIdx.x;
    if (i < count16B) ((int4*)dst)[i] = make_int4(0, 0, 0, 0);
}

// rows1: valid source rows (rows >= rows1 zero-filled)
__global__ __launch_bounds__(TPB)
void wassemble_k(const float* __restrict__ S1, int ld1, int c1, int rows1,
                 const float* __restrict__ S2, int ld2, int c2,
                 int Kp, __hip_bfloat16* __restrict__ dst)
{
    const int c = blockIdx.x * TPB + threadIdx.x;
    const int r = blockIdx.y;
    if (c >= Kp) return;
    float v = 0.f;
    if (r < rows1) {
        if (c < c1) v = S1[(size_t)r * ld1 + c];
        else if (c < c1 + c2) v = S2[(size_t)r * ld2 + (c - c1)];
    }
    dst[(size_t)r * Kp + c] = __float2bfloat16(v);
}

__global__ __launch_bounds__(TPB)
void biasfill_k(const float* __restrict__ b2, const float* __restrict__ b3,
                float* __restrict__ bias3, float* __restrict__ bias4)
{
    int i = blockIdx.x * TPB + threadIdx.x;
    if (i < 512) bias3[i] = (i < 256) ? b2[i] : 0.f;
    else if (i < 768) { int j = i - 512; bias4[j] = (j < 128) ? b3[j] : 0.f; }
}

__global__ __launch_bounds__(TPB)
void sentinel_k(float* __restrict__ out, int ntot, float c)
{
    int i = blockIdx.x * TPB + threadIdx.x;
    if (i < ntot) out[i] = c;
}

// ---------------------------------------------------------------------------
extern "C" void kernel_launch(void* const* d_in, const int* in_sizes, int n_in,
                              void* d_out, int out_size, void* d_ws, size_t ws_size,
                              hipStream_t stream)
{
    static const int EXP_INS[26] = {
        49152, 2097152, 3211264, 1605632, 802816,
        8384, 64, 4096, 64, 134, 2,
        114688, 256, 65536, 256,
        99072, 99072, 256, 66304, 66304, 256,
        33152, 33152, 128, 393, 3 };
    constexpr size_t WS_REQ = 16237824ull * 4ull;

    float code = -1.f;
    if (n_in != 26) code = 64.f;
    else {
        bool ok = true;
        for (int i = 0; i < 26; ++i) ok = ok && (in_sizes[i] == EXP_INS[i]);
        if (!ok) code = 24.f;
    }
    if (code < 0.f && out_size != 2146304) code = 32.f;
    if (code < 0.f && ws_size < WS_REQ)    code = 16.f;
    if (code >= 0.f) {
        sentinel_k<<<dim3((out_size + TPB - 1) / TPB), dim3(TPB), 0, stream>>>(
            (float*)d_out, out_size, code);
        return;
    }

    const float* x_loc  = (const float*)d_in[0];
    const float* x_feat = (const float*)d_in[1];
    const float* p0     = (const float*)d_in[2];
    const float* p1     = (const float*)d_in[3];
    const float* p2     = (const float*)d_in[4];
    const float* Ws1 = (const float*)d_in[5];  const float* bs1 = (const float*)d_in[6];
    const float* Ws2 = (const float*)d_in[7];  const float* bs2 = (const float*)d_in[8];
    const float* Wg  = (const float*)d_in[9];  const float* bg  = (const float*)d_in[10];
    const float* Wl1 = (const float*)d_in[11]; const float* bl1 = (const float*)d_in[12];
    const float* Wl2 = (const float*)d_in[13]; const float* bl2 = (const float*)d_in[14];
    const float* Wr1 = (const float*)d_in[15]; const float* Wn1 = (const float*)d_in[16];
    const float* b1  = (const float*)d_in[17];
    const float* Wr2 = (const float*)d_in[18]; const float* Wn2 = (const float*)d_in[19];
    const float* b2  = (const float*)d_in[20];
    const float* Wr3 = (const float*)d_in[21]; const float* Wn3 = (const float*)d_in[22];
    const float* b3  = (const float*)d_in[23];
    const float* Wloc= (const float*)d_in[24]; const float* bloc= (const float*)d_in[25];

    float* ws = (float*)d_ws;
    float* U  = ws;                       // 8,388,608 f: h1/h2 early, uv later
    float* h1 = U;
    float* h2 = U + 1048576;
    __hip_bfloat16* pooledbf = (__hip_bfloat16*)(ws + 8388608);
    __hip_bfloat16* Xc2      = pooledbf;
    __hip_bfloat16* Xc1 = (__hip_bfloat16*)(ws + 12058624);
    __hip_bfloat16* Xc3 = Xc1;
    float* S     = ws + 15728640;
    float* gridv = S;
    int*   idxp  = (int*)(S + 32768);
    float* Wc1u  = S + 81920;
    float* Wc1v  = S + 147456;
    float* bu1   = S + 212992;
    float* bv1   = S + 213248;
    float* bias3 = S + 213504;
    float* bias4 = S + 214016;
    __hip_bfloat16* Wb1 = (__hip_bfloat16*)(S + 214272);
    __hip_bfloat16* Wb2 = (__hip_bfloat16*)(S + 271616);
    __hip_bfloat16* Wb3 = (__hip_bfloat16*)(S + 386304);
    __hip_bfloat16* Wb4 = (__hip_bfloat16*)(S + 468224);

    float* out_loc  = (float*)d_out;
    float* out_feat = out_loc + (size_t)BATCH * 3 * NPTS;

    dim3 blk(TPB);
    const int GX = NPTS / TPB;   // 16
    Seg z{nullptr, nullptr, 0, 0};
    const int ZPAD16 = 61 * BN / 8;

    // weight prep
    wcomp_k<<<dim3(256, 2), blk, 0, stream>>>(Wr1, Wn1, Wl2, bl2, b1,
                                              Wc1u, Wc1v, bu1, bv1);
    biasfill_k<<<dim3(3), blk, 0, stream>>>(b2, b3, bias3, bias4);
    wassemble_k<<<dim3(2, 256), blk, 0, stream>>>(Wl1, 448, 448, 256, nullptr, 0, 0, 448, Wb1);
    wassemble_k<<<dim3(2, 256), blk, 0, stream>>>(Wr1, 387, 131, 256, Wc1u, 256, 256, 448, Wb2);
    wassemble_k<<<dim3(2, 256), blk, 0, stream>>>(Wn1, 387, 131, 256, Wc1v, 256, 256, 448, Wb2 + 256*448);
    wassemble_k<<<dim3(2, 256), blk, 0, stream>>>(Wr2, 259, 259, 256, nullptr, 0, 0, 320, Wb3);
    wassemble_k<<<dim3(2, 256), blk, 0, stream>>>(Wn2, 259, 259, 256, nullptr, 0, 0, 320, Wb3 + 256*320);
    wassemble_k<<<dim3(2, 128), blk, 0, stream>>>(Wr3, 259, 259, 128, nullptr, 0, 0, 320, Wb4);
    wassemble_k<<<dim3(2, 128), blk, 0, stream>>>(Wn3, 259, 259, 128, nullptr, 0, 0, 320, Wb4 + 128*320);

    // front-end (f32 — precision-critical grid path)
    conv1x1_k<true, 8><<<dim3(GX, 8, BATCH), blk, 0, stream>>>(
        Seg{x_loc, Ws1, 3, 131}, Seg{x_feat, Ws1 + 3, 128, 131}, 2, 131, bs1, h1, 64);
    conv1x1_k<true, 8><<<dim3(GX, 8, BATCH), blk, 0, stream>>>(
        Seg{h1, Ws2, 64, 64}, z, 1, 64, bs2, h2, 64);
    gridconv_k<<<dim3(GX, BATCH), blk, 0, stream>>>(x_loc, h2, Wg, bg, gridv);
    knn_k<<<dim3(NPTS / 16, BATCH), blk, 0, stream>>>(x_loc, idxp);
    gridsample_bf_k<<<dim3(NPTS / 64, 112, BATCH), blk, 0, stream>>>(
        gridv, p0, p1, p2, pooledbf);

    // Xc1 = [loc; x_feat; t; 0-pad]
    castrows_k<<<dim3(GX, 3, BATCH), blk, 0, stream>>>(x_loc, Xc1, 3, 0);
    castrows_k<<<dim3(GX, 128, BATCH), blk, 0, stream>>>(x_feat, Xc1, 128, 3);
    zerobf_k<<<dim3((ZPAD16 + TPB - 1) / TPB), blk, 0, stream>>>(Xc1 + (size_t)387 * BN, ZPAD16);
    // G1: t = relu(Wl1@pooled + bl1) -> Xc1 rows 131+
    gemm_k<1><<<dim3(128, 2), blk, 0, stream>>>(Wb1, pooledbf, bl1, nullptr, Xc1, 448, 131);

    // Xc2 setup (pooledbf consumed by G1)
    castrows_k<<<dim3(GX, 3, BATCH), blk, 0, stream>>>(x_loc, Xc2, 3, 0);
    zerobf_k<<<dim3((ZPAD16 + TPB - 1) / TPB), blk, 0, stream>>>(Xc2 + (size_t)259 * BN, ZPAD16);
    // G2: [u1; v1] = Wb2 @ Xc1 + [bu1; bv1]
    gemm_k<0><<<dim3(128, 4), blk, 0, stream>>>(Wb2, Xc1, bu1, U, nullptr, 448, 0);
    gatherfuse_bf_k<<<dim3(256, BATCH), blk, 0, stream>>>(U, idxp, Xc2);

    // Xc3 setup (Xc1 consumed by G2)
    castrows_k<<<dim3(GX, 3, BATCH), blk, 0, stream>>>(x_loc, Xc3, 3, 0);
    zerobf_k<<<dim3((ZPAD16 + TPB - 1) / TPB), blk, 0, stream>>>(Xc3 + (size_t)259 * BN, ZPAD16);
    // G3: [u2; v2] = Wb3 @ Xc2 + [b2; 0]
    gemm_k<0><<<dim3(128, 4), blk, 0, stream>>>(Wb3, Xc2, bias3, U, nullptr, 320, 0);
    gatherfuse_bf_k<<<dim3(256, BATCH), blk, 0, stream>>>(U, idxp, Xc3);

    // G4: [u3; v3] = Wb4 @ Xc3 + [b3; 0]
    gemm_k<0><<<dim3(128, 2), blk, 0, stream>>>(Wb4, Xc3, bias4, U, nullptr, 320, 0);
    // fused layer-3 gather + Wloc head (channel-parallel, 1024 blocks)
    finalfuse_k<<<dim3(NPTS / 16, BATCH), blk, 0, stream>>>(
        U, idxp, x_loc, Wloc, bloc, out_loc, out_feat);
}

// Round 16
// 275.549 us; speedup vs baseline: 1.5334x; 1.1130x over previous
//
#include <hip/hip_runtime.h>
#include <hip/hip_bf16.h>

#define TPB 256
static constexpr int BATCH = 4;
static constexpr int NPTS  = 4096;
static constexpr int BN    = BATCH * NPTS;   // 16384 columns for all GEMMs

typedef __attribute__((ext_vector_type(8))) short short8v;
typedef __attribute__((ext_vector_type(4))) short short4v;
typedef __attribute__((ext_vector_type(4))) float f32x4;

struct Seg { const float* in; const float* W; int C; int ws; };

__device__ __forceinline__ void gload16(const void* g, void* l) {
    __builtin_amdgcn_global_load_lds(
        (const __attribute__((address_space(1))) void*)g,
        (__attribute__((address_space(3))) void*)l, 16, 0, 0);
}

// ---------------------------------------------------------------------------
// MFMA GEMM (verified): D[m][col] = bias[m] + sum_k A[m][k]*B[k][col]
// ---------------------------------------------------------------------------
template<int EPI>
__global__ __launch_bounds__(256)
void gemm_k(const __hip_bfloat16* __restrict__ A, const __hip_bfloat16* __restrict__ B,
            const float* __restrict__ bias, float* __restrict__ outF,
            __hip_bfloat16* __restrict__ outB, int Kp, int rowOff)
{
    __shared__ short Alds[8192];
    __shared__ short Blds[8704];
    const int tid = threadIdx.x, lane = tid & 63, wid = tid >> 6;
    const int wm = wid & 1, wn = wid >> 1;
    const int n0 = blockIdx.x * 128, m0 = blockIdx.y * 128;

    const char* asrc[4]; short* adst[4];
    #pragma unroll
    for (int t = 0; t < 4; ++t) {
        const int g = (wid * 4 + t) * 64 + lane;
        const int arow = g >> 3, ai = g & 7;
        asrc[t] = (const char*)A +
                  (((size_t)(m0 + arow)) * Kp + ((ai ^ (arow & 7)) << 3)) * 2;
        adst[t] = &Alds[(wid * 4 + t) * 512];
    }
    const char* bsrc[2]; int bkp[2], bc0[2];
    #pragma unroll
    for (int it = 0; it < 2; ++it) {
        const int q = it * 256 + tid;
        bkp[it] = q >> 4;
        bc0[it] = (q & 15) * 8;
        bsrc[it] = (const char*)B +
                   (((size_t)(bkp[it] * 2)) * BN + (n0 + bc0[it])) * 2;
    }

    f32x4 acc[4][4];
    #pragma unroll
    for (int i = 0; i < 4; ++i)
        #pragma unroll
        for (int j = 0; j < 4; ++j) acc[i][j] = (f32x4){0.f, 0.f, 0.f, 0.f};

    const int rl = lane & 15, g4 = lane >> 4;

    const int nkt = Kp >> 6;
    for (int kt = 0; kt < nkt; ++kt) {
        __syncthreads();
        short8v blo[2], bhi[2];
        #pragma unroll
        for (int it = 0; it < 2; ++it) {
            blo[it] = *(const short8v*)(bsrc[it]);
            bhi[it] = *(const short8v*)(bsrc[it] + (size_t)BN * 2);
            bsrc[it] += (size_t)64 * BN * 2;
        }
        #pragma unroll
        for (int t = 0; t < 4; ++t) {
            gload16(asrc[t], adst[t]);
            asrc[t] += 128;
        }
        #pragma unroll
        for (int it = 0; it < 2; ++it) {
            #pragma unroll
            for (int j = 0; j < 8; ++j) {
                const int c = bc0[it] + j;
                const int val = ((int)(unsigned short)blo[it][j]) |
                                (((int)(unsigned short)bhi[it][j]) << 16);
                *(int*)((char*)Blds + c * 136 + bkp[it] * 4) = val;
            }
        }
        __syncthreads();

        #pragma unroll
        for (int ks = 0; ks < 2; ++ks) {
            short8v af[4];
            #pragma unroll
            for (int mf = 0; mf < 4; ++mf) {
                const int row = wm * 64 + mf * 16 + rl;
                const int base = row * 128, sw = (row & 7) << 4;
                const short4v lo = *(const short4v*)((const char*)Alds +
                                    (base + ((ks * 64 + (g4 << 3)) ^ sw)));
                const short4v hi = *(const short4v*)((const char*)Alds +
                                    (base + ((ks * 64 + (g4 << 3) + 32) ^ sw)));
                af[mf] = __builtin_shufflevector(lo, hi, 0,1,2,3,4,5,6,7);
            }
            short8v bfv[4];
            #pragma unroll
            for (int nf = 0; nf < 4; ++nf) {
                const int colr = wn * 64 + nf * 16 + rl;
                const char* bp = (const char*)Blds + colr * 136 + ks * 64 + (g4 << 3);
                const short4v lo = *(const short4v*)bp;
                const short4v hi = *(const short4v*)(bp + 32);
                bfv[nf] = __builtin_shufflevector(lo, hi, 0,1,2,3,4,5,6,7);
            }
            #pragma unroll
            for (int mf = 0; mf < 4; ++mf)
                #pragma unroll
                for (int nf = 0; nf < 4; ++nf)
                    acc[mf][nf] = __builtin_amdgcn_mfma_f32_16x16x32_bf16(
                        af[mf], bfv[nf], acc[mf][nf], 0, 0, 0);
        }
    }

    #pragma unroll
    for (int mf = 0; mf < 4; ++mf) {
        #pragma unroll
        for (int i = 0; i < 4; ++i) {
            const int row = m0 + wm * 64 + mf * 16 + g4 * 4 + i;
            const float bs = bias[row];
            #pragma unroll
            for (int nf = 0; nf < 4; ++nf) {
                const int col = n0 + wn * 64 + nf * 16 + rl;
                float v = acc[mf][nf][i] + bs;
                if (EPI == 1) {
                    v = fmaxf(v, 0.f);
                    outB[(size_t)(rowOff + row) * BN + col] = __float2bfloat16(v);
                } else {
                    outF[(size_t)row * BN + col] = v;
                }
            }
        }
    }
}

// ---------------------------------------------------------------------------
// small f32 conv — h1/h2 only (grid path must stay f32; R13 lesson: bf16
// coordinate error x H/2 through bilinear sampling breaks the output).
// ---------------------------------------------------------------------------
template<bool RELU, int OT>
__global__ __launch_bounds__(TPB)
void conv1x1_k(Seg s0, Seg s1, int nseg, int Ctot,
               const float* __restrict__ bias, float* __restrict__ out, int O)
{
    __shared__ float Wl[131][OT];
    const int n  = blockIdx.x * TPB + threadIdx.x;
    const int o0 = blockIdx.y * OT;
    const int b  = blockIdx.z;
    Seg segs[2] = {s0, s1};
    int off[3]; off[0] = 0;
    #pragma unroll
    for (int k = 0; k < 2; ++k) off[k + 1] = off[k] + (k < nseg ? segs[k].C : 0);
    for (int idx = threadIdx.x; idx < Ctot * OT; idx += TPB) {
        int c = idx / OT, t = idx % OT;
        int k = (nseg > 1 && c >= off[1]) ? 1 : 0;
        Wl[c][t] = segs[k].W[(size_t)(o0 + t) * segs[k].ws + (c - off[k])];
    }
    __syncthreads();
    float acc[OT];
    #pragma unroll
    for (int t = 0; t < OT; ++t) acc[t] = 0.f;
    int cbase = 0;
    for (int k = 0; k < nseg; ++k) {
        const float* ip = segs[k].in + (size_t)b * segs[k].C * NPTS + n;
        const int C = segs[k].C;
        #pragma unroll 4
        for (int cc = 0; cc < C; ++cc) {
            float v = ip[(size_t)cc * NPTS];
            const float4* wr = (const float4*)(&Wl[cbase + cc][0]);
            #pragma unroll
            for (int q = 0; q < OT / 4; ++q) {
                float4 w = wr[q];
                acc[4*q+0] += w.x * v; acc[4*q+1] += w.y * v;
                acc[4*q+2] += w.z * v; acc[4*q+3] += w.w * v;
            }
        }
        cbase += C;
    }
    #pragma unroll
    for (int t = 0; t < OT; ++t) {
        float r = acc[t] + bias[o0 + t];
        if (RELU) r = fmaxf(r, 0.f);
        out[((size_t)b * O + o0 + t) * NPTS + n] = r;
    }
}

// ---------------------------------------------------------------------------
// Fused weight prep: ONE kernel for wcomp + biasfill + all 7 Wb assemblies.
// Block id ranges (1537 blocks total):
//  [0,512)     Wb2 rows (fused Wl2-composition; isv = id>>8, r = id&255)
//  [512,768)   Wb1 row r = id-512
//  [768,1280)  Wb3 rows (isv = (id-768)>>8, r = (id-768)&255)
//  [1280,1536) Wb4 rows (isv = (id-1280)>>7, r = (id-1280)&127)
//  1536        bias3/bias4 fill
// ---------------------------------------------------------------------------
__global__ __launch_bounds__(TPB)
void prepall_k(const float* __restrict__ Wr1, const float* __restrict__ Wn1,
               const float* __restrict__ Wl1, const float* __restrict__ Wl2,
               const float* __restrict__ bl2, const float* __restrict__ b1,
               const float* __restrict__ Wr2, const float* __restrict__ Wn2,
               const float* __restrict__ Wr3, const float* __restrict__ Wn3,
               const float* __restrict__ b2, const float* __restrict__ b3,
               __hip_bfloat16* __restrict__ Wb1, __hip_bfloat16* __restrict__ Wb2,
               __hip_bfloat16* __restrict__ Wb3, __hip_bfloat16* __restrict__ Wb4,
               float* __restrict__ bu1, float* __restrict__ bv1,
               float* __restrict__ bias3, float* __restrict__ bias4)
{
    __shared__ float wrow[256];
    const int id = blockIdx.x, k = threadIdx.x;

    if (id < 512) {                      // Wb2 + composed Wc + biases
        const int isv = id >> 8, r = id & 255;
        const float* W = isv ? Wn1 : Wr1;
        wrow[k] = W[(size_t)r * 387 + 131 + k];
        __syncthreads();
        float acc = 0.f;
        for (int o = 0; o < 256; ++o) acc += wrow[o] * Wl2[(size_t)o * 256 + k];
        const size_t row = (size_t)(isv * 256 + r);
        Wb2[row * 448 + 131 + k] = __float2bfloat16(acc);
        if (k < 131) Wb2[row * 448 + k] = __float2bfloat16(W[(size_t)r * 387 + k]);
        if (k == 0) {
            float s = 0.f;
            for (int o = 0; o < 256; ++o) s += wrow[o] * bl2[o];
            if (isv) bv1[r] = s; else bu1[r] = b1[r] + s;
        }
    } else if (id < 768) {               // Wb1 (256 rows x 448)
        const int r = id - 512;
        #pragma unroll
        for (int t = 0; t < 2; ++t) {
            const int c = t * 256 + k;
            if (c < 448)
                Wb1[(size_t)r * 448 + c] = __float2bfloat16(Wl1[(size_t)r * 448 + c]);
        }
    } else if (id < 1280) {              // Wb3 (512 rows x 320, src 259 cols)
        const int tb = id - 768, isv = tb >> 8, r = tb & 255;
        const float* W = isv ? Wn2 : Wr2;
        const size_t row = (size_t)(isv * 256 + r);
        #pragma unroll
        for (int t = 0; t < 2; ++t) {
            const int c = t * 256 + k;
            if (c < 320) {
                float v = (c < 259) ? W[(size_t)r * 259 + c] : 0.f;
                Wb3[row * 320 + c] = __float2bfloat16(v);
            }
        }
    } else if (id < 1536) {              // Wb4 (256 rows x 320, src 259 cols)
        const int tb = id - 1280, isv = tb >> 7, r = tb & 127;
        const float* W = isv ? Wn3 : Wr3;
        const size_t row = (size_t)(isv * 128 + r);
        #pragma unroll
        for (int t = 0; t < 2; ++t) {
            const int c = t * 256 + k;
            if (c < 320) {
                float v = (c < 259) ? W[(size_t)r * 259 + c] : 0.f;
                Wb4[row * 320 + c] = __float2bfloat16(v);
            }
        }
    } else {                             // bias fills
        #pragma unroll
        for (int t = 0; t < 3; ++t) {
            const int i = t * 256 + k;
            if (i < 512) bias3[i] = (i < 256) ? b2[i] : 0.f;
            else if (i < 768) { int j = i - 512; bias4[j] = (j < 128) ? b3[j] : 0.f; }
        }
    }
}

// ---------------------------------------------------------------------------
// KNN (K=3). Chunked float4(x,y,z,sq) staging, conflict-free; 16q x 16s.
// Strict < serial scan (exact); butterfly merge keeps full lex compare.
// ---------------------------------------------------------------------------
__global__ __launch_bounds__(TPB)
void knn_k(const float* __restrict__ loc, int* __restrict__ idxp)
{
    __shared__ float4 pt[1024];
    const int b = blockIdx.y;
    const float* L = loc + (size_t)b * 3 * NPTS;

    const int ql = threadIdx.x >> 4;
    const int s  = threadIdx.x & 15;
    const int i  = blockIdx.x * 16 + ql;

    const float xi = L[i], yi = L[NPTS + i], zi = L[2 * NPTS + i];
    float sqi;
    {
        #pragma clang fp contract(off)
        sqi = xi * xi + yi * yi + zi * zi;
    }

    float d0 = 3e38f, d1 = 3e38f, d2 = 3e38f;
    int   i0 = 0x7fffffff, i1 = 0x7fffffff, i2 = 0x7fffffff;

    for (int c = 0; c < NPTS / 1024; ++c) {
        __syncthreads();
        {
            const int base = c * 1024;
            #pragma unroll
            for (int t = 0; t < 4; ++t) {
                const int p = t * 256 + threadIdx.x;
                const float x = L[base + p];
                const float y = L[NPTS + base + p];
                const float z = L[2 * NPTS + base + p];
                float sq;
                {
                    #pragma clang fp contract(off)
                    sq = x * x + y * y + z * z;
                }
                pt[p] = make_float4(x, y, z, sq);
            }
        }
        __syncthreads();

        #pragma unroll 4
        for (int k = 0; k < 1024 / 16; ++k) {
            const int jj = (k << 4) | s;
            const float4 p = pt[jj];
            const int j = (c << 10) | jj;
            float d;
            {
                #pragma clang fp contract(off)
                float dot = xi * p.x + yi * p.y + zi * p.z;
                d = (sqi + p.w) - 2.0f * dot;
            }
            d = (j == i) ? 3e38f : d;
            const bool lt2 = d < d2, lt1 = d < d1, lt0 = d < d0;
            d2 = lt1 ? d1 : (lt2 ? d : d2);  i2 = lt1 ? i1 : (lt2 ? j : i2);
            d1 = lt0 ? d0 : (lt1 ? d : d1);  i1 = lt0 ? i0 : (lt1 ? j : i1);
            d0 = lt0 ? d  : d0;              i0 = lt0 ? j  : i0;
        }
    }

    #pragma unroll
    for (int m = 1; m <= 8; m <<= 1) {
        float e0 = __shfl_xor(d0, m), e1 = __shfl_xor(d1, m), e2 = __shfl_xor(d2, m);
        int   j0 = __shfl_xor(i0, m), j1 = __shfl_xor(i1, m), j2 = __shfl_xor(i2, m);
        float ee[3] = {e0, e1, e2};
        int   jj[3] = {j0, j1, j2};
        #pragma unroll
        for (int t = 0; t < 3; ++t) {
            const float e = ee[t]; const int je = jj[t];
            const bool lt2 = (e < d2 || (e == d2 && je < i2));
            const bool lt1 = (e < d1 || (e == d1 && je < i1));
            const bool lt0 = (e < d0 || (e == d0 && je < i0));
            d2 = lt1 ? d1 : (lt2 ? e : d2);  i2 = lt1 ? i1 : (lt2 ? je : i2);
            d1 = lt0 ? d0 : (lt1 ? e : d1);  i1 = lt0 ? i0 : (lt1 ? je : i1);
            d0 = lt0 ? e  : d0;              i0 = lt0 ? je : i0;
        }
    }

    if (s == 0) {
        idxp[0 * BN + b * NPTS + i] = i0;
        idxp[1 * BN + b * NPTS + i] = i1;
        idxp[2 * BN + b * NPTS + i] = i2;
    }
}

// ---------------------------------------------------------------------------
__global__ __launch_bounds__(TPB)
void gridconv_k(const float* __restrict__ loc, const float* __restrict__ h2,
                const float* __restrict__ Wg, const float* __restrict__ bg,
                float* __restrict__ gridv)
{
    const int n = blockIdx.x * TPB + threadIdx.x;
    const int b = blockIdx.y;
    float a0 = bg[0], a1 = bg[1];
    #pragma unroll
    for (int c = 0; c < 3; ++c) {
        float v = loc[((size_t)b * 3 + c) * NPTS + n];
        a0 += Wg[c] * v; a1 += Wg[67 + c] * v;
    }
    const float* hp = h2 + (size_t)b * 64 * NPTS + n;
    #pragma unroll 4
    for (int c = 0; c < 64; ++c) {
        float v = hp[(size_t)c * NPTS];
        a0 += Wg[3 + c] * v; a1 += Wg[70 + c] * v;
    }
    gridv[((size_t)b * 2 + 0) * NPTS + n] = a0;
    gridv[((size_t)b * 2 + 1) * NPTS + n] = a1;
}

// ---------------------------------------------------------------------------
// grid_sample, 4 channels per thread (coords/weights computed once).
// Grid (NPTS/64, 28, BATCH); 4-channel groups never cross pool boundaries
// (64 and 192 are multiples of 4). Per-output math identical to R15.
// ---------------------------------------------------------------------------
__global__ __launch_bounds__(TPB)
void gridsample4_k(const float* __restrict__ gridv, const float* __restrict__ p0,
                   const float* __restrict__ p1, const float* __restrict__ p2,
                   __hip_bfloat16* __restrict__ pooledbf)
{
    const int n     = blockIdx.x * 64 + (threadIdx.x & 63);
    const int cidx0 = blockIdx.y * 16 + (threadIdx.x >> 6) * 4;
    const int b     = blockIdx.z;
    const float* img; int C, H, cbase;
    if (cidx0 < 64)       { img = p0; C = 64;  H = 112; cbase = 0; }
    else if (cidx0 < 192) { img = p1; C = 128; H = 56;  cbase = 64; }
    else                  { img = p2; C = 256; H = 28;  cbase = 192; }
    const float gx = gridv[((size_t)b * 2 + 0) * NPTS + n];
    const float gy = gridv[((size_t)b * 2 + 1) * NPTS + n];
    float wx, wy; int x0, x1, y0, y1;
    {
        #pragma clang fp contract(off)
        float ix  = ((gx + 1.0f) * (float)H - 1.0f) * 0.5f;
        float iy  = ((gy + 1.0f) * (float)H - 1.0f) * 0.5f;
        float ix0 = floorf(ix), iy0 = floorf(iy);
        wx = ix - ix0; wy = iy - iy0;
        x0 = min(max((int)ix0, 0),     H - 1);
        x1 = min(max((int)ix0 + 1, 0), H - 1);
        y0 = min(max((int)iy0, 0),     H - 1);
        y1 = min(max((int)iy0 + 1, 0), H - 1);
    }
    const float w00 = (1.f - wx) * (1.f - wy), w01 = wx * (1.f - wy);
    const float w10 = (1.f - wx) * wy,         w11 = wx * wy;
    const int plane = H * H;
    const float* base = img + ((size_t)b * C + (cidx0 - cbase)) * plane;
    #pragma unroll
    for (int cc = 0; cc < 4; ++cc) {
        const float* pl = base + (size_t)cc * plane;
        float v = pl[y0*H + x0] * w00 + pl[y0*H + x1] * w01
                + pl[y1*H + x0] * w10 + pl[y1*H + x1] * w11;
        pooledbf[(size_t)(cidx0 + cc) * BN + b * NPTS + n] = __float2bfloat16(v);
    }
}

// ---------------------------------------------------------------------------
// Xc1 prep: rows 0..2 loc-cast, 3..130 feat-cast, 387..447 zero. One kernel.
// Grid (NPTS/TPB, 192, BATCH).
// ---------------------------------------------------------------------------
__global__ __launch_bounds__(TPB)
void xc1prep_k(const float* __restrict__ x_loc, const float* __restrict__ x_feat,
               __hip_bfloat16* __restrict__ Xc1)
{
    const int n = blockIdx.x * TPB + threadIdx.x;
    const int y = blockIdx.y, b = blockIdx.z;
    if (y < 3) {
        Xc1[(size_t)y * BN + b * NPTS + n] =
            __float2bfloat16(x_loc[((size_t)b * 3 + y) * NPTS + n]);
    } else if (y < 131) {
        const int c = y - 3;
        Xc1[(size_t)y * BN + b * NPTS + n] =
            __float2bfloat16(x_feat[((size_t)b * 128 + c) * NPTS + n]);
    } else {
        const int row = 387 + (y - 131);
        Xc1[(size_t)row * BN + b * NPTS + n] = __float2bfloat16(0.f);
    }
}

// ---------------------------------------------------------------------------
// Gather + next-layer input prep, one kernel per layer. Grid (320, BATCH):
//  cx<3: loc-cast; 3<=cx<259: feat = relu(u + v[j0]+v[j1]+v[j2]) with
//  LDS-staged v-row; cx>=259: zero row.
// ---------------------------------------------------------------------------
__global__ __launch_bounds__(TPB)
void gatherprep_k(const float* __restrict__ uv, const int* __restrict__ idxp,
                  const float* __restrict__ x_loc, __hip_bfloat16* __restrict__ Xc)
{
    __shared__ float vl[NPTS];   // 16 KB
    const int cx = blockIdx.x, b = blockIdx.y;

    if (cx < 3) {
        #pragma unroll
        for (int t = 0; t < NPTS / TPB; ++t) {
            const int n = t * TPB + threadIdx.x;
            Xc[(size_t)cx * BN + b * NPTS + n] =
                __float2bfloat16(x_loc[((size_t)b * 3 + cx) * NPTS + n]);
        }
        return;
    }
    if (cx >= 259) {
        #pragma unroll
        for (int t = 0; t < NPTS / TPB; ++t) {
            const int n = t * TPB + threadIdx.x;
            Xc[(size_t)cx * BN + b * NPTS + n] = __float2bfloat16(0.f);
        }
        return;
    }
    const int c = cx - 3;
    const float* u = uv + (size_t)c * BN + b * NPTS;
    const float* v = uv + (size_t)(256 + c) * BN + b * NPTS;
    #pragma unroll
    for (int t = 0; t < NPTS / TPB; ++t)
        vl[t * TPB + threadIdx.x] = v[t * TPB + threadIdx.x];
    __syncthreads();
    #pragma unroll
    for (int t = 0; t < NPTS / TPB; ++t) {
        const int n = t * TPB + threadIdx.x;
        const int j0 = idxp[0 * BN + b * NPTS + n] & (NPTS - 1);
        const int j1 = idxp[1 * BN + b * NPTS + n] & (NPTS - 1);
        const int j2 = idxp[2 * BN + b * NPTS + n] & (NPTS - 1);
        float r = u[n] + vl[j0] + vl[j1] + vl[j2];
        Xc[(size_t)cx * BN + b * NPTS + n] = __float2bfloat16(fmaxf(r, 0.f));
    }
}

// ---------------------------------------------------------------------------
// layer-3 gather + Wloc head, channel-parallel (1024 blocks).
// ---------------------------------------------------------------------------
__global__ __launch_bounds__(TPB)
void finalfuse_k(const float* __restrict__ uv, const int* __restrict__ idxp,
                 const float* __restrict__ loc,
                 const float* __restrict__ Wloc, const float* __restrict__ bloc,
                 float* __restrict__ outloc, float* __restrict__ outfeat)
{
    __shared__ float wl[393];
    __shared__ float part[16][16][3];
    for (int idx = threadIdx.x; idx < 393; idx += TPB) wl[idx] = Wloc[idx];
    __syncthreads();

    const int nl = threadIdx.x & 15, cg = threadIdx.x >> 4;
    const int n = blockIdx.x * 16 + nl;
    const int b = blockIdx.y;
    const int j0 = idxp[0 * BN + b * NPTS + n] & (NPTS - 1);
    const int j1 = idxp[1 * BN + b * NPTS + n] & (NPTS - 1);
    const int j2 = idxp[2 * BN + b * NPTS + n] & (NPTS - 1);

    float a0 = 0.f, a1 = 0.f, a2 = 0.f;
    #pragma unroll
    for (int cc = 0; cc < 8; ++cc) {
        const int c = cg * 8 + cc;
        const float* u = uv + (size_t)c * BN + b * NPTS;
        const float* v = uv + (size_t)(128 + c) * BN + b * NPTS;
        float f = fmaxf(u[n] + v[j0] + v[j1] + v[j2], 0.f);
        outfeat[((size_t)b * 128 + c) * NPTS + n] = f;
        a0 += wl[3 + c] * f; a1 += wl[134 + c] * f; a2 += wl[265 + c] * f;
    }
    part[cg][nl][0] = a0; part[cg][nl][1] = a1; part[cg][nl][2] = a2;
    __syncthreads();

    if (cg == 0) {
        float b0 = bloc[0], b1v = bloc[1], b2v = bloc[2];
        float l[3];
        #pragma unroll
        for (int c = 0; c < 3; ++c) {
            float v = loc[((size_t)b * 3 + c) * NPTS + n];
            l[c] = v;
            b0 += wl[c] * v; b1v += wl[131 + c] * v; b2v += wl[262 + c] * v;
        }
        #pragma unroll
        for (int g = 0; g < 16; ++g) {
            b0 += part[g][nl][0]; b1v += part[g][nl][1]; b2v += part[g][nl][2];
        }
        outloc[((size_t)b * 3 + 0) * NPTS + n] = l[0] + tanhf(b0);
        outloc[((size_t)b * 3 + 1) * NPTS + n] = l[1] + tanhf(b1v);
        outloc[((size_t)b * 3 + 2) * NPTS + n] = l[2] + tanhf(b2v);
    }
}

__global__ __launch_bounds__(TPB)
void sentinel_k(float* __restrict__ out, int ntot, float c)
{
    int i = blockIdx.x * TPB + threadIdx.x;
    if (i < ntot) out[i] = c;
}

// ---------------------------------------------------------------------------
extern "C" void kernel_launch(void* const* d_in, const int* in_sizes, int n_in,
                              void* d_out, int out_size, void* d_ws, size_t ws_size,
                              hipStream_t stream)
{
    static const int EXP_INS[26] = {
        49152, 2097152, 3211264, 1605632, 802816,
        8384, 64, 4096, 64, 134, 2,
        114688, 256, 65536, 256,
        99072, 99072, 256, 66304, 66304, 256,
        33152, 33152, 128, 393, 3 };
    constexpr size_t WS_REQ = 16237824ull * 4ull;

    float code = -1.f;
    if (n_in != 26) code = 64.f;
    else {
        bool ok = true;
        for (int i = 0; i < 26; ++i) ok = ok && (in_sizes[i] == EXP_INS[i]);
        if (!ok) code = 24.f;
    }
    if (code < 0.f && out_size != 2146304) code = 32.f;
    if (code < 0.f && ws_size < WS_REQ)    code = 16.f;
    if (code >= 0.f) {
        sentinel_k<<<dim3((out_size + TPB - 1) / TPB), dim3(TPB), 0, stream>>>(
            (float*)d_out, out_size, code);
        return;
    }

    const float* x_loc  = (const float*)d_in[0];
    const float* x_feat = (const float*)d_in[1];
    const float* p0     = (const float*)d_in[2];
    const float* p1     = (const float*)d_in[3];
    const float* p2     = (const float*)d_in[4];
    const float* Ws1 = (const float*)d_in[5];  const float* bs1 = (const float*)d_in[6];
    const float* Ws2 = (const float*)d_in[7];  const float* bs2 = (const float*)d_in[8];
    const float* Wg  = (const float*)d_in[9];  const float* bg  = (const float*)d_in[10];
    const float* Wl1 = (const float*)d_in[11]; const float* bl1 = (const float*)d_in[12];
    const float* Wl2 = (const float*)d_in[13]; const float* bl2 = (const float*)d_in[14];
    const float* Wr1 = (const float*)d_in[15]; const float* Wn1 = (const float*)d_in[16];
    const float* b1  = (const float*)d_in[17];
    const float* Wr2 = (const float*)d_in[18]; const float* Wn2 = (const float*)d_in[19];
    const float* b2  = (const float*)d_in[20];
    const float* Wr3 = (const float*)d_in[21]; const float* Wn3 = (const float*)d_in[22];
    const float* b3  = (const float*)d_in[23];
    const float* Wloc= (const float*)d_in[24]; const float* bloc= (const float*)d_in[25];

    float* ws = (float*)d_ws;
    float* U  = ws;                       // 8,388,608 f: h1/h2 early, uv later
    float* h1 = U;
    float* h2 = U + 1048576;
    __hip_bfloat16* pooledbf = (__hip_bfloat16*)(ws + 8388608);
    __hip_bfloat16* Xc2      = pooledbf;
    __hip_bfloat16* Xc1 = (__hip_bfloat16*)(ws + 12058624);
    __hip_bfloat16* Xc3 = Xc1;
    float* S     = ws + 15728640;
    float* gridv = S;
    int*   idxp  = (int*)(S + 32768);
    float* bu1   = S + 212992;
    float* bv1   = S + 213248;
    float* bias3 = S + 213504;
    float* bias4 = S + 214016;
    __hip_bfloat16* Wb1 = (__hip_bfloat16*)(S + 214272);
    __hip_bfloat16* Wb2 = (__hip_bfloat16*)(S + 271616);
    __hip_bfloat16* Wb3 = (__hip_bfloat16*)(S + 386304);
    __hip_bfloat16* Wb4 = (__hip_bfloat16*)(S + 468224);

    float* out_loc  = (float*)d_out;
    float* out_feat = out_loc + (size_t)BATCH * 3 * NPTS;

    dim3 blk(TPB);
    const int GX = NPTS / TPB;   // 16
    Seg z{nullptr, nullptr, 0, 0};

    // 1) all weight prep in one kernel
    prepall_k<<<dim3(1537), blk, 0, stream>>>(
        Wr1, Wn1, Wl1, Wl2, bl2, b1, Wr2, Wn2, Wr3, Wn3, b2, b3,
        Wb1, Wb2, Wb3, Wb4, bu1, bv1, bias3, bias4);

    // 2-5) front-end (f32 — precision-critical grid path) + knn
    conv1x1_k<true, 8><<<dim3(GX, 8, BATCH), blk, 0, stream>>>(
        Seg{x_loc, Ws1, 3, 131}, Seg{x_feat, Ws1 + 3, 128, 131}, 2, 131, bs1, h1, 64);
    conv1x1_k<true, 8><<<dim3(GX, 8, BATCH), blk, 0, stream>>>(
        Seg{h1, Ws2, 64, 64}, z, 1, 64, bs2, h2, 64);
    gridconv_k<<<dim3(GX, BATCH), blk, 0, stream>>>(x_loc, h2, Wg, bg, gridv);
    knn_k<<<dim3(NPTS / 16, BATCH), blk, 0, stream>>>(x_loc, idxp);

    // 6) pooled (bf16, 4 channels/thread)
    gridsample4_k<<<dim3(NPTS / 64, 28, BATCH), blk, 0, stream>>>(
        gridv, p0, p1, p2, pooledbf);

    // 7) Xc1 rows 0..130 + zero rows 387..447
    xc1prep_k<<<dim3(GX, 192, BATCH), blk, 0, stream>>>(x_loc, x_feat, Xc1);
    // 8) G1: t = relu(Wl1@pooled + bl1) -> Xc1 rows 131..386
    gemm_k<1><<<dim3(128, 2), blk, 0, stream>>>(Wb1, pooledbf, bl1, nullptr, Xc1, 448, 131);

    // 9) G2: [u1; v1] = Wb2 @ Xc1 + [bu1; bv1]  (overwrites h1/h2 — consumed)
    gemm_k<0><<<dim3(128, 4), blk, 0, stream>>>(Wb2, Xc1, bu1, U, nullptr, 448, 0);
    // 10) Xc2 = [loc; relu(u+gather(v)); 0]  (pooledbf region, consumed by G1)
    gatherprep_k<<<dim3(320, BATCH), blk, 0, stream>>>(U, idxp, x_loc, Xc2);

    // 11) G3
    gemm_k<0><<<dim3(128, 4), blk, 0, stream>>>(Wb3, Xc2, bias3, U, nullptr, 320, 0);
    // 12) Xc3 (Xc1 region, consumed by G2)
    gatherprep_k<<<dim3(320, BATCH), blk, 0, stream>>>(U, idxp, x_loc, Xc3);

    // 13) G4
    gemm_k<0><<<dim3(128, 2), blk, 0, stream>>>(Wb4, Xc3, bias4, U, nullptr, 320, 0);
    // 14) fused layer-3 gather + Wloc head
    finalfuse_k<<<dim3(NPTS / 16, BATCH), blk, 0, stream>>>(
        U, idxp, x_loc, Wloc, bloc, out_loc, out_feat);
}